// Round 1
// baseline (4306.133 us; speedup 1.0000x reference)
//
#include <hip/hip_runtime.h>
#include <math.h>

#define B_ 4
#define T_ 8192
#define D_ 1024
#define H_ 8
#define HD_ 128
#define C_ 64
#define N_ 128
#define BT_ (B_*T_)
#define BH_ (B_*H_)

typedef unsigned short ushort_t;
typedef unsigned long long ull_t;

__device__ __forceinline__ void fma4(float4& a, float s, const float4& v) {
  a.x += s*v.x; a.y += s*v.y; a.z += s*v.z; a.w += s*v.w;
}
__device__ __forceinline__ void fma2(float2& a, float s, const float2& v) {
  a.x += s*v.x; a.y += s*v.y;
}
__device__ __forceinline__ float bfu(unsigned int u16) {   // low 16 bits = bf16
  return __uint_as_float(u16 << 16);
}
__device__ __forceinline__ ushort_t f2bf(float f) {
  unsigned int x = __float_as_uint(f);
  x += 0x7FFFu + ((x >> 16) & 1u);
  return (ushort_t)(x >> 16);
}
__device__ __forceinline__ ull_t pack4bf(float a, float b, float c, float d) {
  return (ull_t)f2bf(a) | ((ull_t)f2bf(b) << 16) | ((ull_t)f2bf(c) << 32) | ((ull_t)f2bf(d) << 48);
}

// ---------------------------------------------------------------------------
// Kernel 1: per-token projections -> gate, beta, decay(raw), innorm.
// grid = B*T blocks, 256 threads.
// ---------------------------------------------------------------------------
__global__ __launch_bounds__(256) void k1_proj(
    const float* __restrict__ x, const float* __restrict__ Wg,
    const float* __restrict__ Wb, const float* __restrict__ Wa,
    const float* __restrict__ dt_bias, const float* __restrict__ A_log,
    float* __restrict__ gate_buf, float* __restrict__ beta_buf,
    float* __restrict__ decay_buf, float* __restrict__ innorm_buf) {
  const int row = blockIdx.x;
  const int b = row / T_, t = row % T_;
  const int tid = threadIdx.x;
  __shared__ float xs[D_];
  __shared__ float red[3][H_][4];
  __shared__ float scal[3][H_];
  __shared__ float rnorm[H_];

  ((float4*)xs)[tid] = ((const float4*)(x + (size_t)row * D_))[tid];
  __syncthreads();

  float pg[H_], pb[H_], pa[H_];
  #pragma unroll
  for (int h = 0; h < H_; h++) { pg[h] = 0.f; pb[h] = 0.f; pa[h] = 0.f; }
  for (int i = tid; i < D_; i += 256) {
    float xv = xs[i];
    #pragma unroll
    for (int h = 0; h < H_; h++) {
      pg[h] += xv * Wg[h*D_ + i];
      pb[h] += xv * Wb[h*D_ + i];
      pa[h] += xv * Wa[h*D_ + i];
    }
  }
  const int lane = tid & 63, wv = tid >> 6;
  #pragma unroll
  for (int h = 0; h < H_; h++) {
    float g = pg[h], bb = pb[h], aa = pa[h];
    #pragma unroll
    for (int off = 32; off > 0; off >>= 1) {
      g  += __shfl_down(g, off);
      bb += __shfl_down(bb, off);
      aa += __shfl_down(aa, off);
    }
    if (lane == 0) { red[0][h][wv] = g; red[1][h][wv] = bb; red[2][h][wv] = aa; }
  }
  // per-head sum of squares (32 threads per head, 4 elems each)
  float pn;
  {
    int hh = tid >> 5, e0 = (tid & 31) * 4;
    const float* xh = xs + hh*HD_ + e0;
    pn = xh[0]*xh[0] + xh[1]*xh[1] + xh[2]*xh[2] + xh[3]*xh[3];
  }
  #pragma unroll
  for (int off = 16; off > 0; off >>= 1) pn += __shfl_down(pn, off, 32);
  __syncthreads();
  if ((tid & 31) == 0) rnorm[tid >> 5] = fmaxf(sqrtf(pn), 1e-12f);
  if (tid < 24) {
    int p = tid >> 3, h = tid & 7;
    scal[p][h] = red[p][h][0] + red[p][h][1] + red[p][h][2] + red[p][h][3];
  }
  __syncthreads();
  if (tid < H_) {
    int h = tid;
    float g  = 1.f / (1.f + expf(-scal[0][h]));
    float be = 1.f / (1.f + expf(-scal[1][h]));
    float z  = scal[2][h] + dt_bias[h];
    float sp = (z > 20.f) ? z : log1pf(expf(z));
    float dc = -expf(A_log[h]) * sp;
    size_t idx = (size_t)(b*H_ + h)*T_ + t;
    gate_buf[idx] = g; beta_buf[idx] = be; decay_buf[idx] = dc;
    innorm_buf[idx] = 1.f / rnorm[h];
  }
}

// ---------------------------------------------------------------------------
// GEMM: C[M,N] = A[M,K] @ W[N,K]^T (+ R).  128x128 tile, BK=8, 256 threads.
// ---------------------------------------------------------------------------
__global__ __launch_bounds__(256) void k_gemm(
    const float* __restrict__ A, const float* __restrict__ W,
    const float* __restrict__ R, float* __restrict__ C,
    int M, int N, int K) {
  __shared__ float As[8][132];
  __shared__ float Ws[8][132];
  const int tid = threadIdx.x;
  const int tx = tid & 15, ty = tid >> 4;
  const int row0 = blockIdx.y * 128, col0 = blockIdx.x * 128;
  const int lr = tid >> 1, lk = (tid & 1) * 4;
  float acc[8][8];
  #pragma unroll
  for (int i = 0; i < 8; i++)
    #pragma unroll
    for (int j = 0; j < 8; j++) acc[i][j] = 0.f;
  const float* Ap = A + (size_t)(row0 + lr)*K + lk;
  const float* Wp = W + (size_t)(col0 + lr)*K + lk;
  for (int k0 = 0; k0 < K; k0 += 8) {
    float4 av = *(const float4*)(Ap + k0);
    float4 wv = *(const float4*)(Wp + k0);
    As[lk+0][lr] = av.x; As[lk+1][lr] = av.y; As[lk+2][lr] = av.z; As[lk+3][lr] = av.w;
    Ws[lk+0][lr] = wv.x; Ws[lk+1][lr] = wv.y; Ws[lk+2][lr] = wv.z; Ws[lk+3][lr] = wv.w;
    __syncthreads();
    #pragma unroll
    for (int k = 0; k < 8; k++) {
      float4 a0 = *(const float4*)&As[k][ty*4];
      float4 a1 = *(const float4*)&As[k][64 + ty*4];
      float4 b0 = *(const float4*)&Ws[k][tx*4];
      float4 b1 = *(const float4*)&Ws[k][64 + tx*4];
      float aa[8] = {a0.x,a0.y,a0.z,a0.w,a1.x,a1.y,a1.z,a1.w};
      float bb[8] = {b0.x,b0.y,b0.z,b0.w,b1.x,b1.y,b1.z,b1.w};
      #pragma unroll
      for (int i = 0; i < 8; i++)
        #pragma unroll
        for (int j = 0; j < 8; j++) acc[i][j] += aa[i]*bb[j];
    }
    __syncthreads();
  }
  #pragma unroll
  for (int i = 0; i < 8; i++) {
    int r = row0 + ((i < 4) ? (ty*4 + i) : (64 + ty*4 + i - 4));
    #pragma unroll
    for (int jh = 0; jh < 2; jh++) {
      int c = col0 + jh*64 + tx*4;
      float4 v;
      v.x = acc[i][jh*4+0]; v.y = acc[i][jh*4+1]; v.z = acc[i][jh*4+2]; v.w = acc[i][jh*4+3];
      if (R) {
        float4 rr = *(const float4*)&R[(size_t)r*N + c];
        v.x += rr.x; v.y += rr.y; v.z += rr.z; v.w += rr.w;
      }
      *(float4*)&C[(size_t)r*N + c] = v;
    }
  }
}

// ---------------------------------------------------------------------------
// Kernel 3: per-chunk UT transform.  grid = BH*N, 256 threads.  LDS ~52 KB.
// Pool holds keys (65x132) then aliases v-tile (64x128).
// U packs M (strict lower: U[i][j], j<i) and A^T (upper: U[j][i], i>=j).
// Transforms v -> A@(v*beta) IN PLACE in v_io; writes wkcd (bf16), attn (bf16), dec.
// ---------------------------------------------------------------------------
__global__ __launch_bounds__(256) void k3_chunk(
    const float* __restrict__ x, float* __restrict__ v_io,
    const float* __restrict__ beta_buf, const float* __restrict__ decay_buf,
    const float* __restrict__ innorm_buf,
    ushort_t* __restrict__ wkcd_buf, ushort_t* __restrict__ attn_buf,
    float* __restrict__ dec_buf) {
  const int blk = blockIdx.x;
  const int bh = blk >> 7, n = blk & 127;
  const int b = bh >> 3, h = bh & 7;
  const int t0 = n * C_;
  const int tid = threadIdx.x;
  __shared__ float Pool[65*132];
  __shared__ float U[C_][66];
  __shared__ float dec[C_], beta_s[C_], edec[C_], inn[65];

  if (tid < 65) {
    int tg = t0 - 1 + tid;
    inn[tid] = (tg >= 0) ? innorm_buf[(size_t)bh*T_ + tg] : 0.f;
  }
  if (tid >= 192) {
    int i = tid - 192;
    size_t g = (size_t)bh*T_ + t0 + i;
    beta_s[i] = beta_buf[g];
    dec[i] = decay_buf[g];
  }
  __syncthreads();
  for (int idx = tid; idx < 65*32; idx += 256) {
    int i = idx >> 5, e4 = (idx & 31) * 4;
    int tg = t0 - 1 + i;
    float4 v = {0.f,0.f,0.f,0.f};
    if (tg >= 0) {
      v = *(const float4*)&x[((size_t)b*T_ + tg)*D_ + h*HD_ + e4];
      float s = inn[i];
      v.x*=s; v.y*=s; v.z*=s; v.w*=s;
    }
    *(float4*)&Pool[i*132 + e4] = v;
  }
  __syncthreads();
  if (tid == 0) { float s = 0.f; for (int i = 0; i < C_; i++) { s += dec[i]; dec[i] = s; } }
  __syncthreads();
  if (tid < C_) {
    edec[tid] = expf(dec[tid]);
    dec_buf[(size_t)bh*T_ + t0 + tid] = dec[tid];
  }
  // --- M (strict lower of U) and attn ---
  const int bi = tid >> 4, bj = tid & 15;
  const int i0m = bi*4, j0m = bj*4;
  if (bi >= bj) {
    float m[4][4] = {{0.f}}, am[4][4] = {{0.f}};
    for (int k = 0; k < HD_; k += 4) {
      float4 wb[4];
      #pragma unroll
      for (int c = 0; c < 4; c++) wb[c] = *(const float4*)&Pool[(j0m+c)*132 + k];
      #pragma unroll
      for (int r = 0; r < 4; r++) {
        float4 wa = *(const float4*)&Pool[(i0m+r)*132 + k];
        float4 ra = *(const float4*)&Pool[(i0m+1+r)*132 + k];
        #pragma unroll
        for (int c = 0; c < 4; c++) {
          m[r][c]  += wa.x*wb[c].x + wa.y*wb[c].y + wa.z*wb[c].z + wa.w*wb[c].w;
          am[r][c] += ra.x*wb[c].x + ra.y*wb[c].y + ra.z*wb[c].z + ra.w*wb[c].w;
        }
      }
    }
    #pragma unroll
    for (int r = 0; r < 4; r++) {
      int i = i0m + r;
      #pragma unroll
      for (int c = 0; c < 4; c++) {
        int j = j0m + c;
        if (j < i) U[i][j] = m[r][c] * beta_s[i] * expf(dec[i]-dec[j]);
      }
      float a0 = (j0m+0 <= i) ? am[r][0]*expf(dec[i]-dec[j0m+0]) : 0.f;
      float a1 = (j0m+1 <= i) ? am[r][1]*expf(dec[i]-dec[j0m+1]) : 0.f;
      float a2 = (j0m+2 <= i) ? am[r][2]*expf(dec[i]-dec[j0m+2]) : 0.f;
      float a3 = (j0m+3 <= i) ? am[r][3]*expf(dec[i]-dec[j0m+3]) : 0.f;
      *(ull_t*)&attn_buf[(((size_t)bh*N_ + n)*C_ + i)*C_ + j0m] = pack4bf(a0,a1,a2,a3);
    }
  } else {
    #pragma unroll
    for (int r = 0; r < 4; r++) {
      int i = i0m + r;
      *(ull_t*)&attn_buf[(((size_t)bh*N_ + n)*C_ + i)*C_ + j0m] = 0ull;
    }
  }
  __syncthreads();
  // --- forward substitution: thread j owns column j of A (upper of U) ---
  if (tid < C_) {
    int j = tid;
    U[j][j] = 1.f;
    for (int i = j + 1; i < C_; i++) {
      float s = 0.f;
      for (int l = j; l < i; l++) s += U[i][l] * U[j][l];
      U[j][i] = -s;
    }
  }
  __syncthreads();
  // --- scale wk rows by beta*e^dec ---
  for (int idx = tid; idx < C_*32; idx += 256) {
    int i = idx >> 5, e4 = (idx & 31) * 4;
    float s = beta_s[i] * edec[i];
    float4 v = *(const float4*)&Pool[i*132 + e4];
    v.x*=s; v.y*=s; v.z*=s; v.w*=s;
    *(float4*)&Pool[i*132 + e4] = v;
  }
  __syncthreads();
  // --- wkcd = A @ (wk*beta*e^dec) -> bf16 global ---
  const int i0 = (tid >> 4) * 4, e0 = (tid & 15) * 8;
  {
    float acc[4][8];
    #pragma unroll
    for (int r = 0; r < 4; r++)
      #pragma unroll
      for (int c = 0; c < 8; c++) acc[r][c] = 0.f;
    for (int j = 0; j < i0; j++) {
      float a0=U[j][i0], a1=U[j][i0+1], a2=U[j][i0+2], a3=U[j][i0+3];
      float4 w0 = *(const float4*)&Pool[j*132 + e0];
      float4 w1 = *(const float4*)&Pool[j*132 + e0 + 4];
      float ww[8] = {w0.x,w0.y,w0.z,w0.w,w1.x,w1.y,w1.z,w1.w};
      float aa[4] = {a0,a1,a2,a3};
      #pragma unroll
      for (int r = 0; r < 4; r++)
        #pragma unroll
        for (int c = 0; c < 8; c++) acc[r][c] += aa[r]*ww[c];
    }
    #pragma unroll
    for (int jj = 0; jj < 4; jj++) {
      int j = i0 + jj;
      float4 w0 = *(const float4*)&Pool[j*132 + e0];
      float4 w1 = *(const float4*)&Pool[j*132 + e0 + 4];
      float ww[8] = {w0.x,w0.y,w0.z,w0.w,w1.x,w1.y,w1.z,w1.w};
      for (int r = jj; r < 4; r++) {
        float a = U[j][i0+r];
        #pragma unroll
        for (int c = 0; c < 8; c++) acc[r][c] += a*ww[c];
      }
    }
    #pragma unroll
    for (int r = 0; r < 4; r++) {
      size_t base = ((size_t)bh*T_ + t0 + i0 + r)*HD_ + e0;
      *(ull_t*)&wkcd_buf[base]   = pack4bf(acc[r][0],acc[r][1],acc[r][2],acc[r][3]);
      *(ull_t*)&wkcd_buf[base+4] = pack4bf(acc[r][4],acc[r][5],acc[r][6],acc[r][7]);
    }
  }
  __syncthreads();
  // --- load v tile (beta-scaled) OVER Pool (stride 128) ---
  for (int idx = tid; idx < C_*32; idx += 256) {
    int i = idx >> 5, e4 = (idx & 31) * 4;
    float4 v = *(const float4*)&v_io[((size_t)b*T_ + t0 + i)*D_ + h*HD_ + e4];
    float s = beta_s[i];
    v.x*=s; v.y*=s; v.z*=s; v.w*=s;
    *(float4*)&Pool[i*128 + e4] = v;
  }
  __syncthreads();
  // --- v' = A @ (v*beta) -> write back in place (fp32) ---
  {
    float acc[4][8];
    #pragma unroll
    for (int r = 0; r < 4; r++)
      #pragma unroll
      for (int c = 0; c < 8; c++) acc[r][c] = 0.f;
    for (int j = 0; j < i0; j++) {
      float aa[4] = {U[j][i0], U[j][i0+1], U[j][i0+2], U[j][i0+3]};
      float4 v0 = *(const float4*)&Pool[j*128 + e0];
      float4 v1 = *(const float4*)&Pool[j*128 + e0 + 4];
      float vv[8] = {v0.x,v0.y,v0.z,v0.w,v1.x,v1.y,v1.z,v1.w};
      #pragma unroll
      for (int r = 0; r < 4; r++)
        #pragma unroll
        for (int c = 0; c < 8; c++) acc[r][c] += aa[r]*vv[c];
    }
    #pragma unroll
    for (int jj = 0; jj < 4; jj++) {
      int j = i0 + jj;
      float4 v0 = *(const float4*)&Pool[j*128 + e0];
      float4 v1 = *(const float4*)&Pool[j*128 + e0 + 4];
      float vv[8] = {v0.x,v0.y,v0.z,v0.w,v1.x,v1.y,v1.z,v1.w};
      for (int r = jj; r < 4; r++) {
        float a = U[j][i0+r];
        #pragma unroll
        for (int c = 0; c < 8; c++) acc[r][c] += a*vv[c];
      }
    }
    #pragma unroll
    for (int r = 0; r < 4; r++) {
      size_t base = ((size_t)b*T_ + t0 + i0 + r)*D_ + h*HD_ + e0;
      float4 v0 = {acc[r][0],acc[r][1],acc[r][2],acc[r][3]};
      float4 v1 = {acc[r][4],acc[r][5],acc[r][6],acc[r][7]};
      *(float4*)&v_io[base]     = v0;
      *(float4*)&v_io[base + 4] = v1;
    }
  }
}

// ---------------------------------------------------------------------------
// Kernel 4: inter-chunk scan.  grid = BH*16 (8-col slices), 256 thr. LDS ~69 KB.
// 2 blocks/CU (LDS 70.2KB*2 = 140KB < 160KB) -> 2 waves/SIMD for latency hiding.
// Keys stored RAW; innorm folded into dw[] (S-update) and the o row-scale.
// All global loads for a chunk issue in one phase (single drain).
// Writes gated o IN PLACE over v' in v_io.
// ---------------------------------------------------------------------------
__global__ __launch_bounds__(256, 2) void k4_scan(
    const float* __restrict__ x, float* __restrict__ v_io,
    const ushort_t* __restrict__ wkcd_buf, const ushort_t* __restrict__ attn_buf,
    const float* __restrict__ dec_buf, const float* __restrict__ gate_buf,
    const float* __restrict__ innorm_buf) {
  const int bh = blockIdx.x >> 4;
  const int e0b = (blockIdx.x & 15) * 8;          // 8-column slice of head dim
  const int b = bh >> 3, h = bh & 7;
  const int tid = threadIdx.x;
  __shared__ float S[HD_][12];                    // state slice, stride 12
  __shared__ float PoolF[65*132];                 // raw keys fp32
  __shared__ ushort_t wkcd_s[C_*132];             // bf16 wkcd, row stride 132
  __shared__ ushort_t attn_s[C_][66];
  __shared__ float Vn[C_][12];
  __shared__ float dec_s[C_], edec[C_], dw[C_], gate_s[C_], inn[65];

  for (int idx = tid; idx < HD_*12; idx += 256) (&S[0][0])[idx] = 0.f;

  const int ib = tid >> 2, c2 = (tid & 3) * 2;    // v_new & o: row ib, 2 cols
  const int kr = tid >> 1, cb4 = (tid & 1) * 4;   // S-update: row kr, 4 cols

  for (int n = 0; n < N_; n++) {
    const int t0 = n * C_;
    __syncthreads();
    // ---- phase 0: ALL global loads for this chunk ----
    for (int idx = tid; idx < C_*64; idx += 256) {
      int i = idx >> 6, e2 = idx & 63;
      ((unsigned int*)&wkcd_s[i*132])[e2] =
          ((const unsigned int*)&wkcd_buf[((size_t)bh*T_ + t0 + i)*HD_])[e2];
    }
    for (int idx = tid; idx < C_*32; idx += 256) {
      int i = idx >> 5, e2 = idx & 31;
      ((unsigned int*)&attn_s[i][0])[e2] =
          ((const unsigned int*)&attn_buf[(((size_t)bh*N_ + n)*C_ + i)*C_])[e2];
    }
    for (int idx = tid; idx < 65*32; idx += 256) {
      int i = idx >> 5, e4 = (idx & 31) * 4;
      int tg = t0 - 1 + i;
      float4 v = {0.f,0.f,0.f,0.f};
      if (tg >= 0) v = *(const float4*)&x[((size_t)b*T_ + tg)*D_ + h*HD_ + e4];
      *(float4*)&PoolF[i*132 + e4] = v;           // RAW (no innorm here)
    }
    if (tid < C_) {
      size_t g = (size_t)bh*T_ + t0 + tid;
      float dv = dec_buf[g];
      dec_s[tid] = dv; edec[tid] = expf(dv); gate_s[tid] = gate_buf[g];
    }
    if (tid >= 64 && tid < 129) {
      int i = tid - 64;
      int tg = t0 - 1 + i;
      inn[i] = (tg >= 0) ? innorm_buf[(size_t)bh*T_ + tg] : 0.f;
    }
    __syncthreads();
    if (tid < C_) dw[tid] = expf(dec_s[C_-1] - dec_s[tid]) * inn[tid];  // innorm folded
    // --- v_new = v' - wkcd @ S ---
    {
      const size_t vbase = ((size_t)b*T_ + t0 + ib)*D_ + h*HD_ + e0b + c2;
      float2 a = *(const float2*)&v_io[vbase];
      const ushort_t* wr = &wkcd_s[ib*132];
      for (int k = 0; k < HD_; k += 4) {
        unsigned int u0 = *(const unsigned int*)&wr[k];
        unsigned int u1 = *(const unsigned int*)&wr[k+2];
        float w0 = bfu(u0 & 0xFFFFu), w1 = bfu(u0 >> 16);
        float w2 = bfu(u1 & 0xFFFFu), w3 = bfu(u1 >> 16);
        fma2(a, -w0, *(const float2*)&S[k  ][c2]);
        fma2(a, -w1, *(const float2*)&S[k+1][c2]);
        fma2(a, -w2, *(const float2*)&S[k+2][c2]);
        fma2(a, -w3, *(const float2*)&S[k+3][c2]);
      }
      *(float2*)&Vn[ib][c2] = a;
    }
    __syncthreads();
    // --- o = (rk@S)*innorm*e^dec + attn@v_new; store gated, in place ---
    {
      float2 o = {0.f,0.f};
      const float* rr = &PoolF[(ib+1)*132];
      for (int k = 0; k < HD_; k += 4) {
        float4 r4 = *(const float4*)&rr[k];
        fma2(o, r4.x, *(const float2*)&S[k  ][c2]);
        fma2(o, r4.y, *(const float2*)&S[k+1][c2]);
        fma2(o, r4.z, *(const float2*)&S[k+2][c2]);
        fma2(o, r4.w, *(const float2*)&S[k+3][c2]);
      }
      float sc = edec[ib] * inn[ib+1];
      o.x*=sc; o.y*=sc;
      const int jend = (ib + 4) & ~3;
      for (int j = 0; j < jend; j += 4) {
        unsigned int u0 = *(const unsigned int*)&attn_s[ib][j];
        unsigned int u1 = *(const unsigned int*)&attn_s[ib][j+2];
        fma2(o, bfu(u0 & 0xFFFFu), *(const float2*)&Vn[j  ][c2]);
        fma2(o, bfu(u0 >> 16),     *(const float2*)&Vn[j+1][c2]);
        fma2(o, bfu(u1 & 0xFFFFu), *(const float2*)&Vn[j+2][c2]);
        fma2(o, bfu(u1 >> 16),     *(const float2*)&Vn[j+3][c2]);
      }
      float g = gate_s[ib];
      o.x*=g; o.y*=g;
      *(float2*)&v_io[((size_t)b*T_ + t0 + ib)*D_ + h*HD_ + e0b + c2] = o;
    }
    __syncthreads();   // protect S: o-phase reads S, S-update writes S
    // --- S = S*e^dec[last] + (wk*dw)^T @ v_new  (dw carries innorm) ---
    {
      float el = edec[C_-1];
      float4 s0 = *(const float4*)&S[kr][cb4];
      s0.x*=el; s0.y*=el; s0.z*=el; s0.w*=el;
      for (int i = 0; i < C_; i++) {
        float w = PoolF[i*132 + kr] * dw[i];
        fma4(s0, w, *(const float4*)&Vn[i][cb4]);
      }
      *(float4*)&S[kr][cb4] = s0;
    }
  }
}

// ---------------------------------------------------------------------------
extern "C" void kernel_launch(void* const* d_in, const int* in_sizes, int n_in,
                              void* d_out, int out_size, void* d_ws, size_t ws_size,
                              hipStream_t stream) {
  const float* x       = (const float*)d_in[0];
  const float* W_write = (const float*)d_in[1];
  const float* W_gate  = (const float*)d_in[2];
  const float* W_out   = (const float*)d_in[3];
  const float* W_beta  = (const float*)d_in[4];
  const float* W_alpha = (const float*)d_in[5];
  const float* dt_bias = (const float*)d_in[6];
  const float* A_log   = (const float*)d_in[7];
  float* out = (float*)d_out;

  const size_t SZ_BIG   = (size_t)BT_ * D_;                 // 33.5M elems
  const size_t SZ_ATTN  = (size_t)BH_ * N_ * C_ * C_;       // 16.8M elems
  const size_t SZ_SMALL = (size_t)BH_ * T_;                 // 262K elems

  float*    vraw = (float*)d_ws;                            // fp32, in-place v -> v' -> gated o
  ushort_t* wkcd = (ushort_t*)(vraw + SZ_BIG);              // bf16
  ushort_t* attn = wkcd + SZ_BIG;                           // bf16
  float*    decb = (float*)(attn + SZ_ATTN);
  float*    gateb  = decb + SZ_SMALL;
  float*    betab  = gateb + SZ_SMALL;
  float*    decayb = betab + SZ_SMALL;
  float*    innorm = decayb + SZ_SMALL;
  // total: 134.2 + 67.1 + 33.6 + 5*1.05 MB = ~240 MB

  k1_proj<<<BT_, 256, 0, stream>>>(x, W_gate, W_beta, W_alpha, dt_bias, A_log,
                                   gateb, betab, decayb, innorm);
  k_gemm<<<dim3(D_/128, BT_/128), 256, 0, stream>>>(x, W_write, nullptr, vraw,
                                                    BT_, D_, D_);
  k3_chunk<<<BH_*N_, 256, 0, stream>>>(x, vraw, betab, decayb, innorm,
                                       wkcd, attn, decb);
  k4_scan<<<BH_*16, 256, 0, stream>>>(x, vraw, wkcd, attn, decb, gateb, innorm);
  k_gemm<<<dim3(D_/128, BT_/128), 256, 0, stream>>>(vraw, W_out, x, out,
                                                    BT_, D_, D_);
}

// Round 2
// 2883.091 us; speedup vs baseline: 1.4936x; 1.4936x over previous
//
#include <hip/hip_runtime.h>
#include <math.h>

#define B_ 4
#define T_ 8192
#define D_ 1024
#define H_ 8
#define HD_ 128
#define C_ 64
#define N_ 128
#define BT_ (B_*T_)
#define BH_ (B_*H_)

typedef unsigned short ushort_t;
typedef unsigned long long ull_t;
typedef short s8v __attribute__((ext_vector_type(8)));   // 8 bf16 (4 VGPRs) MFMA A/B frag
typedef float f32x4 __attribute__((ext_vector_type(4))); // MFMA C/D frag

__device__ __forceinline__ void fma4(float4& a, float s, const float4& v) {
  a.x += s*v.x; a.y += s*v.y; a.z += s*v.z; a.w += s*v.w;
}
__device__ __forceinline__ float bfu(unsigned int u16) {   // low 16 bits = bf16
  return __uint_as_float(u16 << 16);
}
__device__ __forceinline__ ushort_t f2bf(float f) {
  unsigned int x = __float_as_uint(f);
  x += 0x7FFFu + ((x >> 16) & 1u);
  return (ushort_t)(x >> 16);
}
__device__ __forceinline__ ull_t pack4bf(float a, float b, float c, float d) {
  return (ull_t)f2bf(a) | ((ull_t)f2bf(b) << 16) | ((ull_t)f2bf(c) << 32) | ((ull_t)f2bf(d) << 48);
}

// ---------------------------------------------------------------------------
// Kernel 1: per-token projections -> gate, beta, decay(raw), innorm.
// grid = B*T blocks, 256 threads.
// ---------------------------------------------------------------------------
__global__ __launch_bounds__(256) void k1_proj(
    const float* __restrict__ x, const float* __restrict__ Wg,
    const float* __restrict__ Wb, const float* __restrict__ Wa,
    const float* __restrict__ dt_bias, const float* __restrict__ A_log,
    float* __restrict__ gate_buf, float* __restrict__ beta_buf,
    float* __restrict__ decay_buf, float* __restrict__ innorm_buf) {
  const int row = blockIdx.x;
  const int b = row / T_, t = row % T_;
  const int tid = threadIdx.x;
  __shared__ float xs[D_];
  __shared__ float red[3][H_][4];
  __shared__ float scal[3][H_];
  __shared__ float rnorm[H_];

  ((float4*)xs)[tid] = ((const float4*)(x + (size_t)row * D_))[tid];
  __syncthreads();

  float pg[H_], pb[H_], pa[H_];
  #pragma unroll
  for (int h = 0; h < H_; h++) { pg[h] = 0.f; pb[h] = 0.f; pa[h] = 0.f; }
  for (int i = tid; i < D_; i += 256) {
    float xv = xs[i];
    #pragma unroll
    for (int h = 0; h < H_; h++) {
      pg[h] += xv * Wg[h*D_ + i];
      pb[h] += xv * Wb[h*D_ + i];
      pa[h] += xv * Wa[h*D_ + i];
    }
  }
  const int lane = tid & 63, wv = tid >> 6;
  #pragma unroll
  for (int h = 0; h < H_; h++) {
    float g = pg[h], bb = pb[h], aa = pa[h];
    #pragma unroll
    for (int off = 32; off > 0; off >>= 1) {
      g  += __shfl_down(g, off);
      bb += __shfl_down(bb, off);
      aa += __shfl_down(aa, off);
    }
    if (lane == 0) { red[0][h][wv] = g; red[1][h][wv] = bb; red[2][h][wv] = aa; }
  }
  float pn;
  {
    int hh = tid >> 5, e0 = (tid & 31) * 4;
    const float* xh = xs + hh*HD_ + e0;
    pn = xh[0]*xh[0] + xh[1]*xh[1] + xh[2]*xh[2] + xh[3]*xh[3];
  }
  #pragma unroll
  for (int off = 16; off > 0; off >>= 1) pn += __shfl_down(pn, off, 32);
  __syncthreads();
  if ((tid & 31) == 0) rnorm[tid >> 5] = fmaxf(sqrtf(pn), 1e-12f);
  if (tid < 24) {
    int p = tid >> 3, h = tid & 7;
    scal[p][h] = red[p][h][0] + red[p][h][1] + red[p][h][2] + red[p][h][3];
  }
  __syncthreads();
  if (tid < H_) {
    int h = tid;
    float g  = 1.f / (1.f + expf(-scal[0][h]));
    float be = 1.f / (1.f + expf(-scal[1][h]));
    float z  = scal[2][h] + dt_bias[h];
    float sp = (z > 20.f) ? z : log1pf(expf(z));
    float dc = -expf(A_log[h]) * sp;
    size_t idx = (size_t)(b*H_ + h)*T_ + t;
    gate_buf[idx] = g; beta_buf[idx] = be; decay_buf[idx] = dc;
    innorm_buf[idx] = 1.f / rnorm[h];
  }
}

// ---------------------------------------------------------------------------
// GEMM: C[M,N] = A[M,K] @ W[N,K]^T (+ R).  128x128 tile, BK=8, 256 threads.
// ---------------------------------------------------------------------------
__global__ __launch_bounds__(256) void k_gemm(
    const float* __restrict__ A, const float* __restrict__ W,
    const float* __restrict__ R, float* __restrict__ C,
    int M, int N, int K) {
  __shared__ float As[8][132];
  __shared__ float Ws[8][132];
  const int tid = threadIdx.x;
  const int tx = tid & 15, ty = tid >> 4;
  const int row0 = blockIdx.y * 128, col0 = blockIdx.x * 128;
  const int lr = tid >> 1, lk = (tid & 1) * 4;
  float acc[8][8];
  #pragma unroll
  for (int i = 0; i < 8; i++)
    #pragma unroll
    for (int j = 0; j < 8; j++) acc[i][j] = 0.f;
  const float* Ap = A + (size_t)(row0 + lr)*K + lk;
  const float* Wp = W + (size_t)(col0 + lr)*K + lk;
  for (int k0 = 0; k0 < K; k0 += 8) {
    float4 av = *(const float4*)(Ap + k0);
    float4 wv = *(const float4*)(Wp + k0);
    As[lk+0][lr] = av.x; As[lk+1][lr] = av.y; As[lk+2][lr] = av.z; As[lk+3][lr] = av.w;
    Ws[lk+0][lr] = wv.x; Ws[lk+1][lr] = wv.y; Ws[lk+2][lr] = wv.z; Ws[lk+3][lr] = wv.w;
    __syncthreads();
    #pragma unroll
    for (int k = 0; k < 8; k++) {
      float4 a0 = *(const float4*)&As[k][ty*4];
      float4 a1 = *(const float4*)&As[k][64 + ty*4];
      float4 b0 = *(const float4*)&Ws[k][tx*4];
      float4 b1 = *(const float4*)&Ws[k][64 + tx*4];
      float aa[8] = {a0.x,a0.y,a0.z,a0.w,a1.x,a1.y,a1.z,a1.w};
      float bb[8] = {b0.x,b0.y,b0.z,b0.w,b1.x,b1.y,b1.z,b1.w};
      #pragma unroll
      for (int i = 0; i < 8; i++)
        #pragma unroll
        for (int j = 0; j < 8; j++) acc[i][j] += aa[i]*bb[j];
    }
    __syncthreads();
  }
  #pragma unroll
  for (int i = 0; i < 8; i++) {
    int r = row0 + ((i < 4) ? (ty*4 + i) : (64 + ty*4 + i - 4));
    #pragma unroll
    for (int jh = 0; jh < 2; jh++) {
      int c = col0 + jh*64 + tx*4;
      float4 v;
      v.x = acc[i][jh*4+0]; v.y = acc[i][jh*4+1]; v.z = acc[i][jh*4+2]; v.w = acc[i][jh*4+3];
      if (R) {
        float4 rr = *(const float4*)&R[(size_t)r*N + c];
        v.x += rr.x; v.y += rr.y; v.z += rr.z; v.w += rr.w;
      }
      *(float4*)&C[(size_t)r*N + c] = v;
    }
  }
}

// ---------------------------------------------------------------------------
// Kernel 3: per-chunk UT transform.  grid = BH*N, 256 threads.  LDS ~52 KB.
// ---------------------------------------------------------------------------
__global__ __launch_bounds__(256) void k3_chunk(
    const float* __restrict__ x, float* __restrict__ v_io,
    const float* __restrict__ beta_buf, const float* __restrict__ decay_buf,
    const float* __restrict__ innorm_buf,
    ushort_t* __restrict__ wkcd_buf, ushort_t* __restrict__ attn_buf,
    float* __restrict__ dec_buf) {
  const int blk = blockIdx.x;
  const int bh = blk >> 7, n = blk & 127;
  const int b = bh >> 3, h = bh & 7;
  const int t0 = n * C_;
  const int tid = threadIdx.x;
  __shared__ float Pool[65*132];
  __shared__ float U[C_][66];
  __shared__ float dec[C_], beta_s[C_], edec[C_], inn[65];

  if (tid < 65) {
    int tg = t0 - 1 + tid;
    inn[tid] = (tg >= 0) ? innorm_buf[(size_t)bh*T_ + tg] : 0.f;
  }
  if (tid >= 192) {
    int i = tid - 192;
    size_t g = (size_t)bh*T_ + t0 + i;
    beta_s[i] = beta_buf[g];
    dec[i] = decay_buf[g];
  }
  __syncthreads();
  for (int idx = tid; idx < 65*32; idx += 256) {
    int i = idx >> 5, e4 = (idx & 31) * 4;
    int tg = t0 - 1 + i;
    float4 v = {0.f,0.f,0.f,0.f};
    if (tg >= 0) {
      v = *(const float4*)&x[((size_t)b*T_ + tg)*D_ + h*HD_ + e4];
      float s = inn[i];
      v.x*=s; v.y*=s; v.z*=s; v.w*=s;
    }
    *(float4*)&Pool[i*132 + e4] = v;
  }
  __syncthreads();
  if (tid == 0) { float s = 0.f; for (int i = 0; i < C_; i++) { s += dec[i]; dec[i] = s; } }
  __syncthreads();
  if (tid < C_) {
    edec[tid] = expf(dec[tid]);
    dec_buf[(size_t)bh*T_ + t0 + tid] = dec[tid];
  }
  const int bi = tid >> 4, bj = tid & 15;
  const int i0m = bi*4, j0m = bj*4;
  if (bi >= bj) {
    float m[4][4] = {{0.f}}, am[4][4] = {{0.f}};
    for (int k = 0; k < HD_; k += 4) {
      float4 wb[4];
      #pragma unroll
      for (int c = 0; c < 4; c++) wb[c] = *(const float4*)&Pool[(j0m+c)*132 + k];
      #pragma unroll
      for (int r = 0; r < 4; r++) {
        float4 wa = *(const float4*)&Pool[(i0m+r)*132 + k];
        float4 ra = *(const float4*)&Pool[(i0m+1+r)*132 + k];
        #pragma unroll
        for (int c = 0; c < 4; c++) {
          m[r][c]  += wa.x*wb[c].x + wa.y*wb[c].y + wa.z*wb[c].z + wa.w*wb[c].w;
          am[r][c] += ra.x*wb[c].x + ra.y*wb[c].y + ra.z*wb[c].z + ra.w*wb[c].w;
        }
      }
    }
    #pragma unroll
    for (int r = 0; r < 4; r++) {
      int i = i0m + r;
      #pragma unroll
      for (int c = 0; c < 4; c++) {
        int j = j0m + c;
        if (j < i) U[i][j] = m[r][c] * beta_s[i] * expf(dec[i]-dec[j]);
      }
      float a0 = (j0m+0 <= i) ? am[r][0]*expf(dec[i]-dec[j0m+0]) : 0.f;
      float a1 = (j0m+1 <= i) ? am[r][1]*expf(dec[i]-dec[j0m+1]) : 0.f;
      float a2 = (j0m+2 <= i) ? am[r][2]*expf(dec[i]-dec[j0m+2]) : 0.f;
      float a3 = (j0m+3 <= i) ? am[r][3]*expf(dec[i]-dec[j0m+3]) : 0.f;
      *(ull_t*)&attn_buf[(((size_t)bh*N_ + n)*C_ + i)*C_ + j0m] = pack4bf(a0,a1,a2,a3);
    }
  } else {
    #pragma unroll
    for (int r = 0; r < 4; r++) {
      int i = i0m + r;
      *(ull_t*)&attn_buf[(((size_t)bh*N_ + n)*C_ + i)*C_ + j0m] = 0ull;
    }
  }
  __syncthreads();
  if (tid < C_) {
    int j = tid;
    U[j][j] = 1.f;
    for (int i = j + 1; i < C_; i++) {
      float s = 0.f;
      for (int l = j; l < i; l++) s += U[i][l] * U[j][l];
      U[j][i] = -s;
    }
  }
  __syncthreads();
  for (int idx = tid; idx < C_*32; idx += 256) {
    int i = idx >> 5, e4 = (idx & 31) * 4;
    float s = beta_s[i] * edec[i];
    float4 v = *(const float4*)&Pool[i*132 + e4];
    v.x*=s; v.y*=s; v.z*=s; v.w*=s;
    *(float4*)&Pool[i*132 + e4] = v;
  }
  __syncthreads();
  const int i0 = (tid >> 4) * 4, e0 = (tid & 15) * 8;
  {
    float acc[4][8];
    #pragma unroll
    for (int r = 0; r < 4; r++)
      #pragma unroll
      for (int c = 0; c < 8; c++) acc[r][c] = 0.f;
    for (int j = 0; j < i0; j++) {
      float a0=U[j][i0], a1=U[j][i0+1], a2=U[j][i0+2], a3=U[j][i0+3];
      float4 w0 = *(const float4*)&Pool[j*132 + e0];
      float4 w1 = *(const float4*)&Pool[j*132 + e0 + 4];
      float ww[8] = {w0.x,w0.y,w0.z,w0.w,w1.x,w1.y,w1.z,w1.w};
      float aa[4] = {a0,a1,a2,a3};
      #pragma unroll
      for (int r = 0; r < 4; r++)
        #pragma unroll
        for (int c = 0; c < 8; c++) acc[r][c] += aa[r]*ww[c];
    }
    #pragma unroll
    for (int jj = 0; jj < 4; jj++) {
      int j = i0 + jj;
      float4 w0 = *(const float4*)&Pool[j*132 + e0];
      float4 w1 = *(const float4*)&Pool[j*132 + e0 + 4];
      float ww[8] = {w0.x,w0.y,w0.z,w0.w,w1.x,w1.y,w1.z,w1.w};
      for (int r = jj; r < 4; r++) {
        float a = U[j][i0+r];
        #pragma unroll
        for (int c = 0; c < 8; c++) acc[r][c] += a*ww[c];
      }
    }
    #pragma unroll
    for (int r = 0; r < 4; r++) {
      size_t base = ((size_t)bh*T_ + t0 + i0 + r)*HD_ + e0;
      *(ull_t*)&wkcd_buf[base]   = pack4bf(acc[r][0],acc[r][1],acc[r][2],acc[r][3]);
      *(ull_t*)&wkcd_buf[base+4] = pack4bf(acc[r][4],acc[r][5],acc[r][6],acc[r][7]);
    }
  }
  __syncthreads();
  for (int idx = tid; idx < C_*32; idx += 256) {
    int i = idx >> 5, e4 = (idx & 31) * 4;
    float4 v = *(const float4*)&v_io[((size_t)b*T_ + t0 + i)*D_ + h*HD_ + e4];
    float s = beta_s[i];
    v.x*=s; v.y*=s; v.z*=s; v.w*=s;
    *(float4*)&Pool[i*128 + e4] = v;
  }
  __syncthreads();
  {
    float acc[4][8];
    #pragma unroll
    for (int r = 0; r < 4; r++)
      #pragma unroll
      for (int c = 0; c < 8; c++) acc[r][c] = 0.f;
    for (int j = 0; j < i0; j++) {
      float aa[4] = {U[j][i0], U[j][i0+1], U[j][i0+2], U[j][i0+3]};
      float4 v0 = *(const float4*)&Pool[j*128 + e0];
      float4 v1 = *(const float4*)&Pool[j*128 + e0 + 4];
      float vv[8] = {v0.x,v0.y,v0.z,v0.w,v1.x,v1.y,v1.z,v1.w};
      #pragma unroll
      for (int r = 0; r < 4; r++)
        #pragma unroll
        for (int c = 0; c < 8; c++) acc[r][c] += aa[r]*vv[c];
    }
    #pragma unroll
    for (int jj = 0; jj < 4; jj++) {
      int j = i0 + jj;
      float4 v0 = *(const float4*)&Pool[j*128 + e0];
      float4 v1 = *(const float4*)&Pool[j*128 + e0 + 4];
      float vv[8] = {v0.x,v0.y,v0.z,v0.w,v1.x,v1.y,v1.z,v1.w};
      for (int r = jj; r < 4; r++) {
        float a = U[j][i0+r];
        #pragma unroll
        for (int c = 0; c < 8; c++) acc[r][c] += a*vv[c];
      }
    }
    #pragma unroll
    for (int r = 0; r < 4; r++) {
      size_t base = ((size_t)b*T_ + t0 + i0 + r)*D_ + h*HD_ + e0;
      float4 v0 = {acc[r][0],acc[r][1],acc[r][2],acc[r][3]};
      float4 v1 = {acc[r][4],acc[r][5],acc[r][6],acc[r][7]};
      *(float4*)&v_io[base]     = v0;
      *(float4*)&v_io[base + 4] = v1;
    }
  }
}

// ---------------------------------------------------------------------------
// Kernel 4 (MFMA): inter-chunk scan.  grid = BH*4 (32-col e-quarters), 512 thr.
// S (128 x 32 f32) carried in accumulator regs across all 128 chunks.
// Per chunk: St(hi/lo bf16) <- S; v_new = v' + (-wkcd)@S (MFMA);
// o = sc*(rk@S) + attn@v_new (MFMA); S = el*S + (wk*dwn)^T@v_new (MFMA).
// All LDS tiles padded so row stride = 4 banks mod 32 -> 2-way conflicts (free).
// Next-chunk keys/wkcd/attn prefetched into registers (T14).
// ---------------------------------------------------------------------------
__global__ __launch_bounds__(512, 2) void k4_mfma(
    const float* __restrict__ x, float* __restrict__ v_io,
    const ushort_t* __restrict__ wkcd_buf, const ushort_t* __restrict__ attn_buf,
    const float* __restrict__ dec_buf, const float* __restrict__ gate_buf,
    const float* __restrict__ innorm_buf) {
  const int bh = blockIdx.x >> 2;
  const int eq = blockIdx.x & 3;
  const int e0b = eq * 32;
  const int b = bh >> 3, h = bh & 7;
  const int tid = threadIdx.x;
  const int w = tid >> 6, lane = tid & 63;
  const int l15 = lane & 15, l4 = lane >> 4;
  const int mt = w >> 1, nt = w & 1;      // v_new/o tile: rows mt*16.., cols nt*16..

  __shared__ ushort_t Krm[64*136];   // keys[t0+t][d] raw bf16 (rk rows), stride 136
  __shared__ ushort_t Kt [128*72];   // keys^T: Kt[d][i] = keys[t0-1+i][d], stride 72
  __shared__ ushort_t Wn [64*136];   // -wkcd bf16
  __shared__ ushort_t At [64*72];    // attn bf16
  __shared__ ushort_t Sth[32*136];   // S hi bf16, [e][d]
  __shared__ ushort_t Stl[32*136];   // S lo bf16
  __shared__ ushort_t Vt [32*72];    // v_new^T bf16, [e][t]
  __shared__ float dec_s[64], gate_s[64], sc_s[64], dwn_s[64];

  f32x4 Sacc[2];
  #pragma unroll
  for (int et = 0; et < 2; et++)
    #pragma unroll
    for (int r = 0; r < 4; r++) Sacc[et][r] = 0.f;

  float4 kf[5], wf[2], af;

  auto PF = [&](int nn) {
    const int tb = nn * C_ - 1;
    #pragma unroll
    for (int k = 0; k < 5; k++) {
      int idx = tid + 512*k;
      float4 v = {0.f,0.f,0.f,0.f};
      if (idx < 2080) {
        int row = idx >> 5, q = idx & 31;
        int tg = tb + row;
        if (tg >= 0) v = *(const float4*)&x[((size_t)b*T_ + tg)*D_ + h*HD_ + q*4];
      }
      kf[k] = v;
    }
    #pragma unroll
    for (int k = 0; k < 2; k++) {
      int p = tid + 512*k;
      wf[k] = *(const float4*)&wkcd_buf[((size_t)bh*T_ + nn*C_)*HD_ + p*8];
    }
    af = *(const float4*)&attn_buf[(((size_t)bh*N_ + nn)*C_)*C_ + (size_t)tid*8];
  };

  PF(0);

  for (int n = 0; n < N_; n++) {
    const int t0 = n * C_;
    // ===== A: stage LDS from PF regs; St <- Sacc; issue v'/smalls loads =====
    #pragma unroll
    for (int k = 0; k < 5; k++) {
      int idx = tid + 512*k;
      if (idx < 2080) {
        int row = idx >> 5, q = idx & 31;
        float4 v = kf[k];
        ushort_t b0 = f2bf(v.x), b1 = f2bf(v.y), b2 = f2bf(v.z), b3 = f2bf(v.w);
        if (row >= 1)
          *(ull_t*)&Krm[(row-1)*136 + q*4] =
              (ull_t)b0 | ((ull_t)b1<<16) | ((ull_t)b2<<32) | ((ull_t)b3<<48);
        if (row <= 63) {
          Kt[(q*4+0)*72 + row] = b0;
          Kt[(q*4+1)*72 + row] = b1;
          Kt[(q*4+2)*72 + row] = b2;
          Kt[(q*4+3)*72 + row] = b3;
        }
      }
    }
    #pragma unroll
    for (int k = 0; k < 2; k++) {
      int p = tid + 512*k;
      int row = p >> 4, col = (p & 15) * 8;
      int4 u = *(int4*)&wf[k];
      u.x ^= 0x80008000; u.y ^= 0x80008000; u.z ^= 0x80008000; u.w ^= 0x80008000;
      *(int4*)&Wn[row*136 + col] = u;
    }
    {
      int row = tid >> 3, col = (tid & 7) * 8;
      *(float4*)&At[row*72 + col] = af;
    }
    // St (hi/lo) from Sacc
    #pragma unroll
    for (int et = 0; et < 2; et++) {
      int e = et*16 + l15;
      int d0 = w*16 + l4*4;
      ull_t ph = 0, pl = 0;
      #pragma unroll
      for (int r = 0; r < 4; r++) {
        float s = Sacc[et][r];
        ushort_t hb = f2bf(s);
        ushort_t lb = f2bf(s - bfu(hb));
        ph |= (ull_t)hb << (16*r);
        pl |= (ull_t)lb << (16*r);
      }
      *(ull_t*)&Sth[e*136 + d0] = ph;
      *(ull_t*)&Stl[e*136 + d0] = pl;
    }
    // v' C-init loads (this chunk)
    float vpf[4];
    #pragma unroll
    for (int r = 0; r < 4; r++)
      vpf[r] = v_io[((size_t)b*T_ + t0 + mt*16 + l4*4 + r)*D_ + h*HD_ + e0b + nt*16 + l15];
    // smalls
    float ipr = 0.f, icr = 0.f;
    if (tid < 64) {
      size_t g = (size_t)bh*T_ + t0 + tid;
      dec_s[tid]  = dec_buf[g];
      gate_s[tid] = gate_buf[g];
      icr = innorm_buf[g];
      ipr = (t0 - 1 + tid >= 0) ? innorm_buf[g - 1] : 0.f;
    }
    __syncthreads();   // (1)
    if (tid < 64) {
      float dv = dec_s[tid], d63 = dec_s[63];
      sc_s[tid]  = expf(dv) * icr;            // edec[t] * innorm[t0+t]
      dwn_s[tid] = expf(d63 - dv) * ipr;      // exp(declast-dec[t]) * innorm[t0-1+t]
    }
    if (n + 1 < N_) PF(n + 1);                // overlap next-chunk loads with compute
    // ===== B: v_new = v' + (-wkcd)@(Shi+Slo) =====
    f32x4 acc;
    acc[0] = vpf[0]; acc[1] = vpf[1]; acc[2] = vpf[2]; acc[3] = vpf[3];
    #pragma unroll
    for (int ks = 0; ks < 4; ks++) {
      s8v a  = *(const s8v*)&Wn [(mt*16 + l15)*136 + ks*32 + l4*8];
      s8v sh = *(const s8v*)&Sth[(nt*16 + l15)*136 + ks*32 + l4*8];
      s8v sl = *(const s8v*)&Stl[(nt*16 + l15)*136 + ks*32 + l4*8];
      acc = __builtin_amdgcn_mfma_f32_16x16x32_bf16(a, sh, acc, 0, 0, 0);
      acc = __builtin_amdgcn_mfma_f32_16x16x32_bf16(a, sl, acc, 0, 0, 0);
    }
    {
      ull_t pv = 0;
      #pragma unroll
      for (int r = 0; r < 4; r++) pv |= (ull_t)f2bf(acc[r]) << (16*r);
      *(ull_t*)&Vt[(nt*16 + l15)*72 + mt*16 + l4*4] = pv;
    }
    __syncthreads();   // (2)
    // ===== C: o = sc*(rk@S) + attn@v_new; gate; store =====
    {
      f32x4 o;
      o[0] = 0.f; o[1] = 0.f; o[2] = 0.f; o[3] = 0.f;
      #pragma unroll
      for (int ks = 0; ks < 4; ks++) {
        s8v a  = *(const s8v*)&Krm[(mt*16 + l15)*136 + ks*32 + l4*8];
        s8v sh = *(const s8v*)&Sth[(nt*16 + l15)*136 + ks*32 + l4*8];
        s8v sl = *(const s8v*)&Stl[(nt*16 + l15)*136 + ks*32 + l4*8];
        o = __builtin_amdgcn_mfma_f32_16x16x32_bf16(a, sh, o, 0, 0, 0);
        o = __builtin_amdgcn_mfma_f32_16x16x32_bf16(a, sl, o, 0, 0, 0);
      }
      #pragma unroll
      for (int r = 0; r < 4; r++) o[r] *= sc_s[mt*16 + l4*4 + r];
      #pragma unroll
      for (int ks = 0; ks < 2; ks++) {
        s8v a  = *(const s8v*)&At[(mt*16 + l15)*72 + ks*32 + l4*8];
        s8v bv = *(const s8v*)&Vt[(nt*16 + l15)*72 + ks*32 + l4*8];
        o = __builtin_amdgcn_mfma_f32_16x16x32_bf16(a, bv, o, 0, 0, 0);
      }
      #pragma unroll
      for (int r = 0; r < 4; r++) {
        float g = gate_s[mt*16 + l4*4 + r];
        v_io[((size_t)b*T_ + t0 + mt*16 + l4*4 + r)*D_ + h*HD_ + e0b + nt*16 + l15] = o[r] * g;
      }
    }
    // ===== D: S = el*S + (wk*dwn)^T @ v_new =====
    {
      float el = expf(dec_s[63]);
      #pragma unroll
      for (int et = 0; et < 2; et++)
        #pragma unroll
        for (int r = 0; r < 4; r++) Sacc[et][r] *= el;
      s8v a0, a1;
      #pragma unroll
      for (int ks = 0; ks < 2; ks++) {
        s8v kt = *(const s8v*)&Kt[(w*16 + l15)*72 + ks*32 + l4*8];
        int i0 = ks*32 + l4*8;
        s8v am;
        #pragma unroll
        for (int e = 0; e < 8; e++) {
          float f = bfu((ushort_t)kt[e]) * dwn_s[i0 + e];
          am[e] = (short)f2bf(f);
        }
        if (ks == 0) a0 = am; else a1 = am;
      }
      #pragma unroll
      for (int et = 0; et < 2; et++) {
        s8v b0 = *(const s8v*)&Vt[(et*16 + l15)*72 +      l4*8];
        s8v b1 = *(const s8v*)&Vt[(et*16 + l15)*72 + 32 + l4*8];
        Sacc[et] = __builtin_amdgcn_mfma_f32_16x16x32_bf16(a0, b0, Sacc[et], 0, 0, 0);
        Sacc[et] = __builtin_amdgcn_mfma_f32_16x16x32_bf16(a1, b1, Sacc[et], 0, 0, 0);
      }
    }
    __syncthreads();   // (3) protect LDS vs next chunk's staging
  }
}

// ---------------------------------------------------------------------------
extern "C" void kernel_launch(void* const* d_in, const int* in_sizes, int n_in,
                              void* d_out, int out_size, void* d_ws, size_t ws_size,
                              hipStream_t stream) {
  const float* x       = (const float*)d_in[0];
  const float* W_write = (const float*)d_in[1];
  const float* W_gate  = (const float*)d_in[2];
  const float* W_out   = (const float*)d_in[3];
  const float* W_beta  = (const float*)d_in[4];
  const float* W_alpha = (const float*)d_in[5];
  const float* dt_bias = (const float*)d_in[6];
  const float* A_log   = (const float*)d_in[7];
  float* out = (float*)d_out;

  const size_t SZ_BIG   = (size_t)BT_ * D_;
  const size_t SZ_ATTN  = (size_t)BH_ * N_ * C_ * C_;
  const size_t SZ_SMALL = (size_t)BH_ * T_;

  float*    vraw = (float*)d_ws;
  ushort_t* wkcd = (ushort_t*)(vraw + SZ_BIG);
  ushort_t* attn = wkcd + SZ_BIG;
  float*    decb = (float*)(attn + SZ_ATTN);
  float*    gateb  = decb + SZ_SMALL;
  float*    betab  = gateb + SZ_SMALL;
  float*    decayb = betab + SZ_SMALL;
  float*    innorm = decayb + SZ_SMALL;

  k1_proj<<<BT_, 256, 0, stream>>>(x, W_gate, W_beta, W_alpha, dt_bias, A_log,
                                   gateb, betab, decayb, innorm);
  k_gemm<<<dim3(D_/128, BT_/128), 256, 0, stream>>>(x, W_write, nullptr, vraw,
                                                    BT_, D_, D_);
  k3_chunk<<<BH_*N_, 256, 0, stream>>>(x, vraw, betab, decayb, innorm,
                                       wkcd, attn, decb);
  k4_mfma<<<BH_*4, 512, 0, stream>>>(x, vraw, wkcd, attn, decb, gateb, innorm);
  k_gemm<<<dim3(D_/128, BT_/128), 256, 0, stream>>>(vraw, W_out, x, out,
                                                    BT_, D_, D_);
}

// Round 4
// 1668.473 us; speedup vs baseline: 2.5809x; 1.7280x over previous
//
#include <hip/hip_runtime.h>
#include <math.h>

#define B_ 4
#define T_ 8192
#define D_ 1024
#define H_ 8
#define HD_ 128
#define C_ 64
#define N_ 128
#define BT_ (B_*T_)
#define BH_ (B_*H_)

typedef unsigned short ushort_t;
typedef unsigned long long ull_t;
typedef short s8v __attribute__((ext_vector_type(8)));   // 8 bf16 (4 VGPRs) MFMA A/B frag
typedef float f32x4 __attribute__((ext_vector_type(4))); // MFMA C/D frag

__device__ __forceinline__ void fma4(float4& a, float s, const float4& v) {
  a.x += s*v.x; a.y += s*v.y; a.z += s*v.z; a.w += s*v.w;
}
__device__ __forceinline__ float bfu(unsigned int u16) {   // low 16 bits = bf16
  return __uint_as_float(u16 << 16);
}
__device__ __forceinline__ ushort_t f2bf(float f) {
  unsigned int x = __float_as_uint(f);
  x += 0x7FFFu + ((x >> 16) & 1u);
  return (ushort_t)(x >> 16);
}
__device__ __forceinline__ ull_t pack4bf(float a, float b, float c, float d) {
  return (ull_t)f2bf(a) | ((ull_t)f2bf(b) << 16) | ((ull_t)f2bf(c) << 32) | ((ull_t)f2bf(d) << 48);
}

// ---------------------------------------------------------------------------
// Kernel 1: per-token projections -> gate, beta, decay(raw), innorm.
// grid = B*T blocks, 256 threads.
// ---------------------------------------------------------------------------
__global__ __launch_bounds__(256) void k1_proj(
    const float* __restrict__ x, const float* __restrict__ Wg,
    const float* __restrict__ Wb, const float* __restrict__ Wa,
    const float* __restrict__ dt_bias, const float* __restrict__ A_log,
    float* __restrict__ gate_buf, float* __restrict__ beta_buf,
    float* __restrict__ decay_buf, float* __restrict__ innorm_buf) {
  const int row = blockIdx.x;
  const int b = row / T_, t = row % T_;
  const int tid = threadIdx.x;
  __shared__ float xs[D_];
  __shared__ float red[3][H_][4];
  __shared__ float scal[3][H_];
  __shared__ float rnorm[H_];

  ((float4*)xs)[tid] = ((const float4*)(x + (size_t)row * D_))[tid];
  __syncthreads();

  float pg[H_], pb[H_], pa[H_];
  #pragma unroll
  for (int h = 0; h < H_; h++) { pg[h] = 0.f; pb[h] = 0.f; pa[h] = 0.f; }
  for (int i = tid; i < D_; i += 256) {
    float xv = xs[i];
    #pragma unroll
    for (int h = 0; h < H_; h++) {
      pg[h] += xv * Wg[h*D_ + i];
      pb[h] += xv * Wb[h*D_ + i];
      pa[h] += xv * Wa[h*D_ + i];
    }
  }
  const int lane = tid & 63, wv = tid >> 6;
  #pragma unroll
  for (int h = 0; h < H_; h++) {
    float g = pg[h], bb = pb[h], aa = pa[h];
    #pragma unroll
    for (int off = 32; off > 0; off >>= 1) {
      g  += __shfl_down(g, off);
      bb += __shfl_down(bb, off);
      aa += __shfl_down(aa, off);
    }
    if (lane == 0) { red[0][h][wv] = g; red[1][h][wv] = bb; red[2][h][wv] = aa; }
  }
  float pn;
  {
    int hh = tid >> 5, e0 = (tid & 31) * 4;
    const float* xh = xs + hh*HD_ + e0;
    pn = xh[0]*xh[0] + xh[1]*xh[1] + xh[2]*xh[2] + xh[3]*xh[3];
  }
  #pragma unroll
  for (int off = 16; off > 0; off >>= 1) pn += __shfl_down(pn, off, 32);
  __syncthreads();
  if ((tid & 31) == 0) rnorm[tid >> 5] = fmaxf(sqrtf(pn), 1e-12f);
  if (tid < 24) {
    int p = tid >> 3, h = tid & 7;
    scal[p][h] = red[p][h][0] + red[p][h][1] + red[p][h][2] + red[p][h][3];
  }
  __syncthreads();
  if (tid < H_) {
    int h = tid;
    float g  = 1.f / (1.f + expf(-scal[0][h]));
    float be = 1.f / (1.f + expf(-scal[1][h]));
    float z  = scal[2][h] + dt_bias[h];
    float sp = (z > 20.f) ? z : log1pf(expf(z));
    float dc = -expf(A_log[h]) * sp;
    size_t idx = (size_t)(b*H_ + h)*T_ + t;
    gate_buf[idx] = g; beta_buf[idx] = be; decay_buf[idx] = dc;
    innorm_buf[idx] = 1.f / rnorm[h];
  }
}

// ---------------------------------------------------------------------------
// GEMM (bf16 MFMA): C[M,N] = A[M,K] @ W[N,K]^T (+ R).
// 128x128 tile, BK=32, 256 thr (4 waves x 64x64 out).  fp32 inputs converted
// to bf16 during reg->LDS staging.  XCD-aware block swizzle.  LDS 20 KB.
// ---------------------------------------------------------------------------
__global__ __launch_bounds__(256) void k_gemm_bf16(
    const float* __restrict__ A, const float* __restrict__ W,
    const float* __restrict__ R, float* __restrict__ C,
    int M, int N, int K) {
  __shared__ ushort_t La[128*40];   // stride 40 bf16 = 80 B (2-way conflicts only)
  __shared__ ushort_t Lw[128*40];
  const int tid = threadIdx.x;
  const int w = tid >> 6, lane = tid & 63;
  const int l15 = lane & 15, l4 = lane >> 4;
  const int wr = w >> 1, wc = w & 1;          // wave tile: rows wr*64, cols wc*64

  // XCD-aware swizzle (grid is 1-D, nwg % 8 == 0)
  const int nwg = gridDim.x;
  const int NB = N >> 7;
  const int bid = blockIdx.x;
  const int swz = (bid & 7) * (nwg >> 3) + (bid >> 3);
  const int row0 = (swz / NB) * 128, col0 = (swz % NB) * 128;

  f32x4 acc[4][4];
  #pragma unroll
  for (int m = 0; m < 4; m++)
    #pragma unroll
    for (int n = 0; n < 4; n++)
      #pragma unroll
      for (int r = 0; r < 4; r++) acc[m][n][r] = 0.f;

  float4 pa[2][2], pw[2][2];
  auto LOAD = [&](int k0) {
    #pragma unroll
    for (int s = 0; s < 2; s++) {
      int slot = tid + s*256;
      int rw = slot >> 2, kg = (slot & 3) * 8;
      const float* ap = A + (size_t)(row0 + rw)*K + k0 + kg;
      pa[s][0] = *(const float4*)ap; pa[s][1] = *(const float4*)(ap + 4);
      const float* wp = W + (size_t)(col0 + rw)*K + k0 + kg;
      pw[s][0] = *(const float4*)wp; pw[s][1] = *(const float4*)(wp + 4);
    }
  };

  LOAD(0);
  for (int k0 = 0; k0 < K; k0 += 32) {
    // stage regs -> LDS (fp32 -> bf16)
    #pragma unroll
    for (int s = 0; s < 2; s++) {
      int slot = tid + s*256;
      int rw = slot >> 2, kg = (slot & 3) * 8;
      int4 ua, uw;
      ua.x = (int)f2bf(pa[s][0].x) | ((int)f2bf(pa[s][0].y) << 16);
      ua.y = (int)f2bf(pa[s][0].z) | ((int)f2bf(pa[s][0].w) << 16);
      ua.z = (int)f2bf(pa[s][1].x) | ((int)f2bf(pa[s][1].y) << 16);
      ua.w = (int)f2bf(pa[s][1].z) | ((int)f2bf(pa[s][1].w) << 16);
      uw.x = (int)f2bf(pw[s][0].x) | ((int)f2bf(pw[s][0].y) << 16);
      uw.y = (int)f2bf(pw[s][0].z) | ((int)f2bf(pw[s][0].w) << 16);
      uw.z = (int)f2bf(pw[s][1].x) | ((int)f2bf(pw[s][1].y) << 16);
      uw.w = (int)f2bf(pw[s][1].z) | ((int)f2bf(pw[s][1].w) << 16);
      *(int4*)&La[rw*40 + kg] = ua;
      *(int4*)&Lw[rw*40 + kg] = uw;
    }
    __syncthreads();
    if (k0 + 32 < K) LOAD(k0 + 32);    // overlap next-tile loads with MFMA
    s8v af[4], bf[4];
    #pragma unroll
    for (int m = 0; m < 4; m++)
      af[m] = *(const s8v*)&La[(wr*64 + m*16 + l15)*40 + l4*8];
    #pragma unroll
    for (int n = 0; n < 4; n++)
      bf[n] = *(const s8v*)&Lw[(wc*64 + n*16 + l15)*40 + l4*8];
    #pragma unroll
    for (int m = 0; m < 4; m++)
      #pragma unroll
      for (int n = 0; n < 4; n++)
        acc[m][n] = __builtin_amdgcn_mfma_f32_16x16x32_bf16(af[m], bf[n], acc[m][n], 0, 0, 0);
    __syncthreads();
  }

  // epilogue: C row = row0+wr*64+m*16+l4*4+r, col = col0+wc*64+n*16+l15
  #pragma unroll
  for (int m = 0; m < 4; m++) {
    #pragma unroll
    for (int r = 0; r < 4; r++) {
      int row = row0 + wr*64 + m*16 + l4*4 + r;
      size_t base = (size_t)row * N + col0 + wc*64 + l15;
      #pragma unroll
      for (int n = 0; n < 4; n++) {
        float v = acc[m][n][r];
        if (R) v += R[base + n*16];
        C[base + n*16] = v;
      }
    }
  }
}

// ---------------------------------------------------------------------------
// Kernel 3: per-chunk UT transform.  grid = BH*N, 256 threads.  LDS ~52 KB.
// ---------------------------------------------------------------------------
__global__ __launch_bounds__(256) void k3_chunk(
    const float* __restrict__ x, float* __restrict__ v_io,
    const float* __restrict__ beta_buf, const float* __restrict__ decay_buf,
    const float* __restrict__ innorm_buf,
    ushort_t* __restrict__ wkcd_buf, ushort_t* __restrict__ attn_buf,
    float* __restrict__ dec_buf) {
  const int blk = blockIdx.x;
  const int bh = blk >> 7, n = blk & 127;
  const int b = bh >> 3, h = bh & 7;
  const int t0 = n * C_;
  const int tid = threadIdx.x;
  __shared__ float Pool[65*132];
  __shared__ float U[C_][66];
  __shared__ float dec[C_], beta_s[C_], edec[C_], inn[65];

  if (tid < 65) {
    int tg = t0 - 1 + tid;
    inn[tid] = (tg >= 0) ? innorm_buf[(size_t)bh*T_ + tg] : 0.f;
  }
  if (tid >= 192) {
    int i = tid - 192;
    size_t g = (size_t)bh*T_ + t0 + i;
    beta_s[i] = beta_buf[g];
    dec[i] = decay_buf[g];
  }
  __syncthreads();
  for (int idx = tid; idx < 65*32; idx += 256) {
    int i = idx >> 5, e4 = (idx & 31) * 4;
    int tg = t0 - 1 + i;
    float4 v = {0.f,0.f,0.f,0.f};
    if (tg >= 0) {
      v = *(const float4*)&x[((size_t)b*T_ + tg)*D_ + h*HD_ + e4];
      float s = inn[i];
      v.x*=s; v.y*=s; v.z*=s; v.w*=s;
    }
    *(float4*)&Pool[i*132 + e4] = v;
  }
  __syncthreads();
  if (tid == 0) { float s = 0.f; for (int i = 0; i < C_; i++) { s += dec[i]; dec[i] = s; } }
  __syncthreads();
  if (tid < C_) {
    edec[tid] = expf(dec[tid]);
    dec_buf[(size_t)bh*T_ + t0 + tid] = dec[tid];
  }
  const int bi = tid >> 4, bj = tid & 15;
  const int i0m = bi*4, j0m = bj*4;
  if (bi >= bj) {
    float m[4][4] = {{0.f}}, am[4][4] = {{0.f}};
    for (int k = 0; k < HD_; k += 4) {
      float4 wb[4];
      #pragma unroll
      for (int c = 0; c < 4; c++) wb[c] = *(const float4*)&Pool[(j0m+c)*132 + k];
      #pragma unroll
      for (int r = 0; r < 4; r++) {
        float4 wa = *(const float4*)&Pool[(i0m+r)*132 + k];
        float4 ra = *(const float4*)&Pool[(i0m+1+r)*132 + k];
        #pragma unroll
        for (int c = 0; c < 4; c++) {
          m[r][c]  += wa.x*wb[c].x + wa.y*wb[c].y + wa.z*wb[c].z + wa.w*wb[c].w;
          am[r][c] += ra.x*wb[c].x + ra.y*wb[c].y + ra.z*wb[c].z + ra.w*wb[c].w;
        }
      }
    }
    #pragma unroll
    for (int r = 0; r < 4; r++) {
      int i = i0m + r;
      #pragma unroll
      for (int c = 0; c < 4; c++) {
        int j = j0m + c;
        if (j < i) U[i][j] = m[r][c] * beta_s[i] * expf(dec[i]-dec[j]);
      }
      float a0 = (j0m+0 <= i) ? am[r][0]*expf(dec[i]-dec[j0m+0]) : 0.f;
      float a1 = (j0m+1 <= i) ? am[r][1]*expf(dec[i]-dec[j0m+1]) : 0.f;
      float a2 = (j0m+2 <= i) ? am[r][2]*expf(dec[i]-dec[j0m+2]) : 0.f;
      float a3 = (j0m+3 <= i) ? am[r][3]*expf(dec[i]-dec[j0m+3]) : 0.f;
      *(ull_t*)&attn_buf[(((size_t)bh*N_ + n)*C_ + i)*C_ + j0m] = pack4bf(a0,a1,a2,a3);
    }
  } else {
    #pragma unroll
    for (int r = 0; r < 4; r++) {
      int i = i0m + r;
      *(ull_t*)&attn_buf[(((size_t)bh*N_ + n)*C_ + i)*C_ + j0m] = 0ull;
    }
  }
  __syncthreads();
  if (tid < C_) {
    int j = tid;
    U[j][j] = 1.f;
    for (int i = j + 1; i < C_; i++) {
      float s = 0.f;
      for (int l = j; l < i; l++) s += U[i][l] * U[j][l];
      U[j][i] = -s;
    }
  }
  __syncthreads();
  for (int idx = tid; idx < C_*32; idx += 256) {
    int i = idx >> 5, e4 = (idx & 31) * 4;
    float s = beta_s[i] * edec[i];
    float4 v = *(const float4*)&Pool[i*132 + e4];
    v.x*=s; v.y*=s; v.z*=s; v.w*=s;
    *(float4*)&Pool[i*132 + e4] = v;
  }
  __syncthreads();
  const int i0 = (tid >> 4) * 4, e0 = (tid & 15) * 8;
  {
    float acc[4][8];
    #pragma unroll
    for (int r = 0; r < 4; r++)
      #pragma unroll
      for (int c = 0; c < 8; c++) acc[r][c] = 0.f;
    for (int j = 0; j < i0; j++) {
      float a0=U[j][i0], a1=U[j][i0+1], a2=U[j][i0+2], a3=U[j][i0+3];
      float4 w0 = *(const float4*)&Pool[j*132 + e0];
      float4 w1 = *(const float4*)&Pool[j*132 + e0 + 4];
      float ww[8] = {w0.x,w0.y,w0.z,w0.w,w1.x,w1.y,w1.z,w1.w};
      float aa[4] = {a0,a1,a2,a3};
      #pragma unroll
      for (int r = 0; r < 4; r++)
        #pragma unroll
        for (int c = 0; c < 8; c++) acc[r][c] += aa[r]*ww[c];
    }
    #pragma unroll
    for (int jj = 0; jj < 4; jj++) {
      int j = i0 + jj;
      float4 w0 = *(const float4*)&Pool[j*132 + e0];
      float4 w1 = *(const float4*)&Pool[j*132 + e0 + 4];
      float ww[8] = {w0.x,w0.y,w0.z,w0.w,w1.x,w1.y,w1.z,w1.w};
      for (int r = jj; r < 4; r++) {
        float a = U[j][i0+r];
        #pragma unroll
        for (int c = 0; c < 8; c++) acc[r][c] += a*ww[c];
      }
    }
    #pragma unroll
    for (int r = 0; r < 4; r++) {
      size_t base = ((size_t)bh*T_ + t0 + i0 + r)*HD_ + e0;
      *(ull_t*)&wkcd_buf[base]   = pack4bf(acc[r][0],acc[r][1],acc[r][2],acc[r][3]);
      *(ull_t*)&wkcd_buf[base+4] = pack4bf(acc[r][4],acc[r][5],acc[r][6],acc[r][7]);
    }
  }
  __syncthreads();
  for (int idx = tid; idx < C_*32; idx += 256) {
    int i = idx >> 5, e4 = (idx & 31) * 4;
    float4 v = *(const float4*)&v_io[((size_t)b*T_ + t0 + i)*D_ + h*HD_ + e4];
    float s = beta_s[i];
    v.x*=s; v.y*=s; v.z*=s; v.w*=s;
    *(float4*)&Pool[i*128 + e4] = v;
  }
  __syncthreads();
  {
    float acc[4][8];
    #pragma unroll
    for (int r = 0; r < 4; r++)
      #pragma unroll
      for (int c = 0; c < 8; c++) acc[r][c] = 0.f;
    for (int j = 0; j < i0; j++) {
      float aa[4] = {U[j][i0], U[j][i0+1], U[j][i0+2], U[j][i0+3]};
      float4 v0 = *(const float4*)&Pool[j*128 + e0];
      float4 v1 = *(const float4*)&Pool[j*128 + e0 + 4];
      float vv[8] = {v0.x,v0.y,v0.z,v0.w,v1.x,v1.y,v1.z,v1.w};
      #pragma unroll
      for (int r = 0; r < 4; r++)
        #pragma unroll
        for (int c = 0; c < 8; c++) acc[r][c] += aa[r]*vv[c];
    }
    #pragma unroll
    for (int jj = 0; jj < 4; jj++) {
      int j = i0 + jj;
      float4 v0 = *(const float4*)&Pool[j*128 + e0];
      float4 v1 = *(const float4*)&Pool[j*128 + e0 + 4];
      float vv[8] = {v0.x,v0.y,v0.z,v0.w,v1.x,v1.y,v1.z,v1.w};
      for (int r = jj; r < 4; r++) {
        float a = U[j][i0+r];
        #pragma unroll
        for (int c = 0; c < 8; c++) acc[r][c] += a*vv[c];
      }
    }
    #pragma unroll
    for (int r = 0; r < 4; r++) {
      size_t base = ((size_t)b*T_ + t0 + i0 + r)*D_ + h*HD_ + e0;
      float4 v0 = {acc[r][0],acc[r][1],acc[r][2],acc[r][3]};
      float4 v1 = {acc[r][4],acc[r][5],acc[r][6],acc[r][7]};
      *(float4*)&v_io[base]     = v0;
      *(float4*)&v_io[base + 4] = v1;
    }
  }
}

// ---------------------------------------------------------------------------
// Kernel 4 (MFMA): inter-chunk scan.  grid = BH*4 (32-col e-quarters), 512 thr.
// ---------------------------------------------------------------------------
__global__ __launch_bounds__(512, 2) void k4_mfma(
    const float* __restrict__ x, float* __restrict__ v_io,
    const ushort_t* __restrict__ wkcd_buf, const ushort_t* __restrict__ attn_buf,
    const float* __restrict__ dec_buf, const float* __restrict__ gate_buf,
    const float* __restrict__ innorm_buf) {
  const int bh = blockIdx.x >> 2;
  const int eq = blockIdx.x & 3;
  const int e0b = eq * 32;
  const int b = bh >> 3, h = bh & 7;
  const int tid = threadIdx.x;
  const int w = tid >> 6, lane = tid & 63;
  const int l15 = lane & 15, l4 = lane >> 4;
  const int mt = w >> 1, nt = w & 1;

  __shared__ ushort_t Krm[64*136];
  __shared__ ushort_t Kt [128*72];
  __shared__ ushort_t Wn [64*136];
  __shared__ ushort_t At [64*72];
  __shared__ ushort_t Sth[32*136];
  __shared__ ushort_t Stl[32*136];
  __shared__ ushort_t Vt [32*72];
  __shared__ float dec_s[64], gate_s[64], sc_s[64], dwn_s[64];

  f32x4 Sacc[2];
  #pragma unroll
  for (int et = 0; et < 2; et++)
    #pragma unroll
    for (int r = 0; r < 4; r++) Sacc[et][r] = 0.f;

  float4 kf[5], wf[2], af;

  auto PF = [&](int nn) {
    const int tb = nn * C_ - 1;
    #pragma unroll
    for (int k = 0; k < 5; k++) {
      int idx = tid + 512*k;
      float4 v = {0.f,0.f,0.f,0.f};
      if (idx < 2080) {
        int row = idx >> 5, q = idx & 31;
        int tg = tb + row;
        if (tg >= 0) v = *(const float4*)&x[((size_t)b*T_ + tg)*D_ + h*HD_ + q*4];
      }
      kf[k] = v;
    }
    #pragma unroll
    for (int k = 0; k < 2; k++) {
      int p = tid + 512*k;
      wf[k] = *(const float4*)&wkcd_buf[((size_t)bh*T_ + nn*C_)*HD_ + p*8];
    }
    af = *(const float4*)&attn_buf[(((size_t)bh*N_ + nn)*C_)*C_ + (size_t)tid*8];
  };

  PF(0);

  for (int n = 0; n < N_; n++) {
    const int t0 = n * C_;
    #pragma unroll
    for (int k = 0; k < 5; k++) {
      int idx = tid + 512*k;
      if (idx < 2080) {
        int row = idx >> 5, q = idx & 31;
        float4 v = kf[k];
        ushort_t b0 = f2bf(v.x), b1 = f2bf(v.y), b2 = f2bf(v.z), b3 = f2bf(v.w);
        if (row >= 1)
          *(ull_t*)&Krm[(row-1)*136 + q*4] =
              (ull_t)b0 | ((ull_t)b1<<16) | ((ull_t)b2<<32) | ((ull_t)b3<<48);
        if (row <= 63) {
          Kt[(q*4+0)*72 + row] = b0;
          Kt[(q*4+1)*72 + row] = b1;
          Kt[(q*4+2)*72 + row] = b2;
          Kt[(q*4+3)*72 + row] = b3;
        }
      }
    }
    #pragma unroll
    for (int k = 0; k < 2; k++) {
      int p = tid + 512*k;
      int row = p >> 4, col = (p & 15) * 8;
      int4 u = *(int4*)&wf[k];
      u.x ^= 0x80008000; u.y ^= 0x80008000; u.z ^= 0x80008000; u.w ^= 0x80008000;
      *(int4*)&Wn[row*136 + col] = u;
    }
    {
      int row = tid >> 3, col = (tid & 7) * 8;
      *(float4*)&At[row*72 + col] = af;
    }
    #pragma unroll
    for (int et = 0; et < 2; et++) {
      int e = et*16 + l15;
      int d0 = w*16 + l4*4;
      ull_t ph = 0, pl = 0;
      #pragma unroll
      for (int r = 0; r < 4; r++) {
        float s = Sacc[et][r];
        ushort_t hb = f2bf(s);
        ushort_t lb = f2bf(s - bfu(hb));
        ph |= (ull_t)hb << (16*r);
        pl |= (ull_t)lb << (16*r);
      }
      *(ull_t*)&Sth[e*136 + d0] = ph;
      *(ull_t*)&Stl[e*136 + d0] = pl;
    }
    float vpf[4];
    #pragma unroll
    for (int r = 0; r < 4; r++)
      vpf[r] = v_io[((size_t)b*T_ + t0 + mt*16 + l4*4 + r)*D_ + h*HD_ + e0b + nt*16 + l15];
    float ipr = 0.f, icr = 0.f;
    if (tid < 64) {
      size_t g = (size_t)bh*T_ + t0 + tid;
      dec_s[tid]  = dec_buf[g];
      gate_s[tid] = gate_buf[g];
      icr = innorm_buf[g];
      ipr = (t0 - 1 + tid >= 0) ? innorm_buf[g - 1] : 0.f;
    }
    __syncthreads();   // (1)
    if (tid < 64) {
      float dv = dec_s[tid], d63 = dec_s[63];
      sc_s[tid]  = expf(dv) * icr;
      dwn_s[tid] = expf(d63 - dv) * ipr;
    }
    if (n + 1 < N_) PF(n + 1);
    f32x4 acc;
    acc[0] = vpf[0]; acc[1] = vpf[1]; acc[2] = vpf[2]; acc[3] = vpf[3];
    #pragma unroll
    for (int ks = 0; ks < 4; ks++) {
      s8v a  = *(const s8v*)&Wn [(mt*16 + l15)*136 + ks*32 + l4*8];
      s8v sh = *(const s8v*)&Sth[(nt*16 + l15)*136 + ks*32 + l4*8];
      s8v sl = *(const s8v*)&Stl[(nt*16 + l15)*136 + ks*32 + l4*8];
      acc = __builtin_amdgcn_mfma_f32_16x16x32_bf16(a, sh, acc, 0, 0, 0);
      acc = __builtin_amdgcn_mfma_f32_16x16x32_bf16(a, sl, acc, 0, 0, 0);
    }
    {
      ull_t pv = 0;
      #pragma unroll
      for (int r = 0; r < 4; r++) pv |= (ull_t)f2bf(acc[r]) << (16*r);
      *(ull_t*)&Vt[(nt*16 + l15)*72 + mt*16 + l4*4] = pv;
    }
    __syncthreads();   // (2)
    {
      f32x4 o;
      o[0] = 0.f; o[1] = 0.f; o[2] = 0.f; o[3] = 0.f;
      #pragma unroll
      for (int ks = 0; ks < 4; ks++) {
        s8v a  = *(const s8v*)&Krm[(mt*16 + l15)*136 + ks*32 + l4*8];
        s8v sh = *(const s8v*)&Sth[(nt*16 + l15)*136 + ks*32 + l4*8];
        s8v sl = *(const s8v*)&Stl[(nt*16 + l15)*136 + ks*32 + l4*8];
        o = __builtin_amdgcn_mfma_f32_16x16x32_bf16(a, sh, o, 0, 0, 0);
        o = __builtin_amdgcn_mfma_f32_16x16x32_bf16(a, sl, o, 0, 0, 0);
      }
      #pragma unroll
      for (int r = 0; r < 4; r++) o[r] *= sc_s[mt*16 + l4*4 + r];
      #pragma unroll
      for (int ks = 0; ks < 2; ks++) {
        s8v a  = *(const s8v*)&At[(mt*16 + l15)*72 + ks*32 + l4*8];
        s8v bv = *(const s8v*)&Vt[(nt*16 + l15)*72 + ks*32 + l4*8];
        o = __builtin_amdgcn_mfma_f32_16x16x32_bf16(a, bv, o, 0, 0, 0);
      }
      #pragma unroll
      for (int r = 0; r < 4; r++) {
        float g = gate_s[mt*16 + l4*4 + r];
        v_io[((size_t)b*T_ + t0 + mt*16 + l4*4 + r)*D_ + h*HD_ + e0b + nt*16 + l15] = o[r] * g;
      }
    }
    {
      float el = expf(dec_s[63]);
      #pragma unroll
      for (int et = 0; et < 2; et++)
        #pragma unroll
        for (int r = 0; r < 4; r++) Sacc[et][r] *= el;
      s8v a0, a1;
      #pragma unroll
      for (int ks = 0; ks < 2; ks++) {
        s8v kt = *(const s8v*)&Kt[(w*16 + l15)*72 + ks*32 + l4*8];
        int i0 = ks*32 + l4*8;
        s8v am;
        #pragma unroll
        for (int e = 0; e < 8; e++) {
          float f = bfu((ushort_t)kt[e]) * dwn_s[i0 + e];
          am[e] = (short)f2bf(f);
        }
        if (ks == 0) a0 = am; else a1 = am;
      }
      #pragma unroll
      for (int et = 0; et < 2; et++) {
        s8v b0 = *(const s8v*)&Vt[(et*16 + l15)*72 +      l4*8];
        s8v b1 = *(const s8v*)&Vt[(et*16 + l15)*72 + 32 + l4*8];
        Sacc[et] = __builtin_amdgcn_mfma_f32_16x16x32_bf16(a0, b0, Sacc[et], 0, 0, 0);
        Sacc[et] = __builtin_amdgcn_mfma_f32_16x16x32_bf16(a1, b1, Sacc[et], 0, 0, 0);
      }
    }
    __syncthreads();   // (3)
  }
}

// ---------------------------------------------------------------------------
extern "C" void kernel_launch(void* const* d_in, const int* in_sizes, int n_in,
                              void* d_out, int out_size, void* d_ws, size_t ws_size,
                              hipStream_t stream) {
  const float* x       = (const float*)d_in[0];
  const float* W_write = (const float*)d_in[1];
  const float* W_gate  = (const float*)d_in[2];
  const float* W_out   = (const float*)d_in[3];
  const float* W_beta  = (const float*)d_in[4];
  const float* W_alpha = (const float*)d_in[5];
  const float* dt_bias = (const float*)d_in[6];
  const float* A_log   = (const float*)d_in[7];
  float* out = (float*)d_out;

  const size_t SZ_BIG   = (size_t)BT_ * D_;
  const size_t SZ_ATTN  = (size_t)BH_ * N_ * C_ * C_;
  const size_t SZ_SMALL = (size_t)BH_ * T_;

  float*    vraw = (float*)d_ws;
  ushort_t* wkcd = (ushort_t*)(vraw + SZ_BIG);
  ushort_t* attn = wkcd + SZ_BIG;
  float*    decb = (float*)(attn + SZ_ATTN);
  float*    gateb  = decb + SZ_SMALL;
  float*    betab  = gateb + SZ_SMALL;
  float*    decayb = betab + SZ_SMALL;
  float*    innorm = decayb + SZ_SMALL;

  const int GEMM_GRID = (BT_/128) * (D_/128);   // 2048, %8==0

  k1_proj<<<BT_, 256, 0, stream>>>(x, W_gate, W_beta, W_alpha, dt_bias, A_log,
                                   gateb, betab, decayb, innorm);
  k_gemm_bf16<<<GEMM_GRID, 256, 0, stream>>>(x, W_write, nullptr, vraw,
                                             BT_, D_, D_);
  k3_chunk<<<BH_*N_, 256, 0, stream>>>(x, vraw, betab, decayb, innorm,
                                       wkcd, attn, decb);
  k4_mfma<<<BH_*4, 512, 0, stream>>>(x, vraw, wkcd, attn, decb, gateb, innorm);
  k_gemm_bf16<<<GEMM_GRID, 256, 0, stream>>>(vraw, W_out, x, out,
                                             BT_, D_, D_);
}

// Round 5
// 1486.999 us; speedup vs baseline: 2.8959x; 1.1220x over previous
//
#include <hip/hip_runtime.h>
#include <math.h>

#define B_ 4
#define T_ 8192
#define D_ 1024
#define H_ 8
#define HD_ 128
#define C_ 64
#define N_ 128
#define BT_ (B_*T_)
#define BH_ (B_*H_)

typedef unsigned short ushort_t;
typedef unsigned long long ull_t;
typedef short s8v __attribute__((ext_vector_type(8)));   // 8 bf16 (4 VGPRs) MFMA A/B frag
typedef float f32x4 __attribute__((ext_vector_type(4))); // MFMA C/D frag

__device__ __forceinline__ void fma4(float4& a, float s, const float4& v) {
  a.x += s*v.x; a.y += s*v.y; a.z += s*v.z; a.w += s*v.w;
}
__device__ __forceinline__ float bfu(unsigned int u16) {   // low 16 bits = bf16
  return __uint_as_float(u16 << 16);
}
__device__ __forceinline__ ushort_t f2bf(float f) {
  unsigned int x = __float_as_uint(f);
  x += 0x7FFFu + ((x >> 16) & 1u);
  return (ushort_t)(x >> 16);
}
__device__ __forceinline__ ull_t pack4bf(float a, float b, float c, float d) {
  return (ull_t)f2bf(a) | ((ull_t)f2bf(b) << 16) | ((ull_t)f2bf(c) << 32) | ((ull_t)f2bf(d) << 48);
}

// ---------------------------------------------------------------------------
// Kernel 1: per-token projections -> gate, beta, decay(raw), innorm.
// grid = B*T blocks, 256 threads.
// ---------------------------------------------------------------------------
__global__ __launch_bounds__(256) void k1_proj(
    const float* __restrict__ x, const float* __restrict__ Wg,
    const float* __restrict__ Wb, const float* __restrict__ Wa,
    const float* __restrict__ dt_bias, const float* __restrict__ A_log,
    float* __restrict__ gate_buf, float* __restrict__ beta_buf,
    float* __restrict__ decay_buf, float* __restrict__ innorm_buf) {
  const int row = blockIdx.x;
  const int b = row / T_, t = row % T_;
  const int tid = threadIdx.x;
  __shared__ float xs[D_];
  __shared__ float red[3][H_][4];
  __shared__ float scal[3][H_];
  __shared__ float rnorm[H_];

  ((float4*)xs)[tid] = ((const float4*)(x + (size_t)row * D_))[tid];
  __syncthreads();

  float pg[H_], pb[H_], pa[H_];
  #pragma unroll
  for (int h = 0; h < H_; h++) { pg[h] = 0.f; pb[h] = 0.f; pa[h] = 0.f; }
  for (int i = tid; i < D_; i += 256) {
    float xv = xs[i];
    #pragma unroll
    for (int h = 0; h < H_; h++) {
      pg[h] += xv * Wg[h*D_ + i];
      pb[h] += xv * Wb[h*D_ + i];
      pa[h] += xv * Wa[h*D_ + i];
    }
  }
  const int lane = tid & 63, wv = tid >> 6;
  #pragma unroll
  for (int h = 0; h < H_; h++) {
    float g = pg[h], bb = pb[h], aa = pa[h];
    #pragma unroll
    for (int off = 32; off > 0; off >>= 1) {
      g  += __shfl_down(g, off);
      bb += __shfl_down(bb, off);
      aa += __shfl_down(aa, off);
    }
    if (lane == 0) { red[0][h][wv] = g; red[1][h][wv] = bb; red[2][h][wv] = aa; }
  }
  float pn;
  {
    int hh = tid >> 5, e0 = (tid & 31) * 4;
    const float* xh = xs + hh*HD_ + e0;
    pn = xh[0]*xh[0] + xh[1]*xh[1] + xh[2]*xh[2] + xh[3]*xh[3];
  }
  #pragma unroll
  for (int off = 16; off > 0; off >>= 1) pn += __shfl_down(pn, off, 32);
  __syncthreads();
  if ((tid & 31) == 0) rnorm[tid >> 5] = fmaxf(sqrtf(pn), 1e-12f);
  if (tid < 24) {
    int p = tid >> 3, h = tid & 7;
    scal[p][h] = red[p][h][0] + red[p][h][1] + red[p][h][2] + red[p][h][3];
  }
  __syncthreads();
  if (tid < H_) {
    int h = tid;
    float g  = 1.f / (1.f + expf(-scal[0][h]));
    float be = 1.f / (1.f + expf(-scal[1][h]));
    float z  = scal[2][h] + dt_bias[h];
    float sp = (z > 20.f) ? z : log1pf(expf(z));
    float dc = -expf(A_log[h]) * sp;
    size_t idx = (size_t)(b*H_ + h)*T_ + t;
    gate_buf[idx] = g; beta_buf[idx] = be; decay_buf[idx] = dc;
    innorm_buf[idx] = 1.f / rnorm[h];
  }
}

// ---------------------------------------------------------------------------
// GEMM (bf16 MFMA): C[M,N] = A[M,K] @ W[N,K]^T (+ R).
// 128x128 tile, BK=32, 256 thr (4 waves x 64x64 out).  fp32 inputs converted
// to bf16 during reg->LDS staging.  XCD-aware block swizzle.  LDS 20 KB.
// ---------------------------------------------------------------------------
__global__ __launch_bounds__(256) void k_gemm_bf16(
    const float* __restrict__ A, const float* __restrict__ W,
    const float* __restrict__ R, float* __restrict__ C,
    int M, int N, int K) {
  __shared__ ushort_t La[128*40];   // stride 40 bf16 = 80 B (2-way conflicts only)
  __shared__ ushort_t Lw[128*40];
  const int tid = threadIdx.x;
  const int w = tid >> 6, lane = tid & 63;
  const int l15 = lane & 15, l4 = lane >> 4;
  const int wr = w >> 1, wc = w & 1;          // wave tile: rows wr*64, cols wc*64

  // XCD-aware swizzle (grid is 1-D, nwg % 8 == 0)
  const int nwg = gridDim.x;
  const int NB = N >> 7;
  const int bid = blockIdx.x;
  const int swz = (bid & 7) * (nwg >> 3) + (bid >> 3);
  const int row0 = (swz / NB) * 128, col0 = (swz % NB) * 128;

  f32x4 acc[4][4];
  #pragma unroll
  for (int m = 0; m < 4; m++)
    #pragma unroll
    for (int n = 0; n < 4; n++)
      #pragma unroll
      for (int r = 0; r < 4; r++) acc[m][n][r] = 0.f;

  float4 pa[2][2], pw[2][2];
  auto LOAD = [&](int k0) {
    #pragma unroll
    for (int s = 0; s < 2; s++) {
      int slot = tid + s*256;
      int rw = slot >> 2, kg = (slot & 3) * 8;
      const float* ap = A + (size_t)(row0 + rw)*K + k0 + kg;
      pa[s][0] = *(const float4*)ap; pa[s][1] = *(const float4*)(ap + 4);
      const float* wp = W + (size_t)(col0 + rw)*K + k0 + kg;
      pw[s][0] = *(const float4*)wp; pw[s][1] = *(const float4*)(wp + 4);
    }
  };

  LOAD(0);
  for (int k0 = 0; k0 < K; k0 += 32) {
    // stage regs -> LDS (fp32 -> bf16)
    #pragma unroll
    for (int s = 0; s < 2; s++) {
      int slot = tid + s*256;
      int rw = slot >> 2, kg = (slot & 3) * 8;
      int4 ua, uw;
      ua.x = (int)f2bf(pa[s][0].x) | ((int)f2bf(pa[s][0].y) << 16);
      ua.y = (int)f2bf(pa[s][0].z) | ((int)f2bf(pa[s][0].w) << 16);
      ua.z = (int)f2bf(pa[s][1].x) | ((int)f2bf(pa[s][1].y) << 16);
      ua.w = (int)f2bf(pa[s][1].z) | ((int)f2bf(pa[s][1].w) << 16);
      uw.x = (int)f2bf(pw[s][0].x) | ((int)f2bf(pw[s][0].y) << 16);
      uw.y = (int)f2bf(pw[s][0].z) | ((int)f2bf(pw[s][0].w) << 16);
      uw.z = (int)f2bf(pw[s][1].x) | ((int)f2bf(pw[s][1].y) << 16);
      uw.w = (int)f2bf(pw[s][1].z) | ((int)f2bf(pw[s][1].w) << 16);
      *(int4*)&La[rw*40 + kg] = ua;
      *(int4*)&Lw[rw*40 + kg] = uw;
    }
    __syncthreads();
    if (k0 + 32 < K) LOAD(k0 + 32);    // overlap next-tile loads with MFMA
    s8v af[4], bf[4];
    #pragma unroll
    for (int m = 0; m < 4; m++)
      af[m] = *(const s8v*)&La[(wr*64 + m*16 + l15)*40 + l4*8];
    #pragma unroll
    for (int n = 0; n < 4; n++)
      bf[n] = *(const s8v*)&Lw[(wc*64 + n*16 + l15)*40 + l4*8];
    #pragma unroll
    for (int m = 0; m < 4; m++)
      #pragma unroll
      for (int n = 0; n < 4; n++)
        acc[m][n] = __builtin_amdgcn_mfma_f32_16x16x32_bf16(af[m], bf[n], acc[m][n], 0, 0, 0);
    __syncthreads();
  }

  // epilogue: C row = row0+wr*64+m*16+l4*4+r, col = col0+wc*64+n*16+l15
  #pragma unroll
  for (int m = 0; m < 4; m++) {
    #pragma unroll
    for (int r = 0; r < 4; r++) {
      int row = row0 + wr*64 + m*16 + l4*4 + r;
      size_t base = (size_t)row * N + col0 + wc*64 + l15;
      #pragma unroll
      for (int n = 0; n < 4; n++) {
        float v = acc[m][n][r];
        if (R) v += R[base + n*16];
        C[base + n*16] = v;
      }
    }
  }
}

// ---------------------------------------------------------------------------
// Kernel 3: per-chunk UT transform.  grid = BH*N, 256 threads.  LDS ~52 KB.
// ---------------------------------------------------------------------------
__global__ __launch_bounds__(256) void k3_chunk(
    const float* __restrict__ x, float* __restrict__ v_io,
    const float* __restrict__ beta_buf, const float* __restrict__ decay_buf,
    const float* __restrict__ innorm_buf,
    ushort_t* __restrict__ wkcd_buf, ushort_t* __restrict__ attn_buf,
    float* __restrict__ dec_buf) {
  const int blk = blockIdx.x;
  const int bh = blk >> 7, n = blk & 127;
  const int b = bh >> 3, h = bh & 7;
  const int t0 = n * C_;
  const int tid = threadIdx.x;
  __shared__ float Pool[65*132];
  __shared__ float U[C_][66];
  __shared__ float dec[C_], beta_s[C_], edec[C_], inn[65];

  if (tid < 65) {
    int tg = t0 - 1 + tid;
    inn[tid] = (tg >= 0) ? innorm_buf[(size_t)bh*T_ + tg] : 0.f;
  }
  if (tid >= 192) {
    int i = tid - 192;
    size_t g = (size_t)bh*T_ + t0 + i;
    beta_s[i] = beta_buf[g];
    dec[i] = decay_buf[g];
  }
  __syncthreads();
  for (int idx = tid; idx < 65*32; idx += 256) {
    int i = idx >> 5, e4 = (idx & 31) * 4;
    int tg = t0 - 1 + i;
    float4 v = {0.f,0.f,0.f,0.f};
    if (tg >= 0) {
      v = *(const float4*)&x[((size_t)b*T_ + tg)*D_ + h*HD_ + e4];
      float s = inn[i];
      v.x*=s; v.y*=s; v.z*=s; v.w*=s;
    }
    *(float4*)&Pool[i*132 + e4] = v;
  }
  __syncthreads();
  if (tid == 0) { float s = 0.f; for (int i = 0; i < C_; i++) { s += dec[i]; dec[i] = s; } }
  __syncthreads();
  if (tid < C_) {
    edec[tid] = expf(dec[tid]);
    dec_buf[(size_t)bh*T_ + t0 + tid] = dec[tid];
  }
  const int bi = tid >> 4, bj = tid & 15;
  const int i0m = bi*4, j0m = bj*4;
  if (bi >= bj) {
    float m[4][4] = {{0.f}}, am[4][4] = {{0.f}};
    for (int k = 0; k < HD_; k += 4) {
      float4 wb[4];
      #pragma unroll
      for (int c = 0; c < 4; c++) wb[c] = *(const float4*)&Pool[(j0m+c)*132 + k];
      #pragma unroll
      for (int r = 0; r < 4; r++) {
        float4 wa = *(const float4*)&Pool[(i0m+r)*132 + k];
        float4 ra = *(const float4*)&Pool[(i0m+1+r)*132 + k];
        #pragma unroll
        for (int c = 0; c < 4; c++) {
          m[r][c]  += wa.x*wb[c].x + wa.y*wb[c].y + wa.z*wb[c].z + wa.w*wb[c].w;
          am[r][c] += ra.x*wb[c].x + ra.y*wb[c].y + ra.z*wb[c].z + ra.w*wb[c].w;
        }
      }
    }
    #pragma unroll
    for (int r = 0; r < 4; r++) {
      int i = i0m + r;
      #pragma unroll
      for (int c = 0; c < 4; c++) {
        int j = j0m + c;
        if (j < i) U[i][j] = m[r][c] * beta_s[i] * expf(dec[i]-dec[j]);
      }
      float a0 = (j0m+0 <= i) ? am[r][0]*expf(dec[i]-dec[j0m+0]) : 0.f;
      float a1 = (j0m+1 <= i) ? am[r][1]*expf(dec[i]-dec[j0m+1]) : 0.f;
      float a2 = (j0m+2 <= i) ? am[r][2]*expf(dec[i]-dec[j0m+2]) : 0.f;
      float a3 = (j0m+3 <= i) ? am[r][3]*expf(dec[i]-dec[j0m+3]) : 0.f;
      *(ull_t*)&attn_buf[(((size_t)bh*N_ + n)*C_ + i)*C_ + j0m] = pack4bf(a0,a1,a2,a3);
    }
  } else {
    #pragma unroll
    for (int r = 0; r < 4; r++) {
      int i = i0m + r;
      *(ull_t*)&attn_buf[(((size_t)bh*N_ + n)*C_ + i)*C_ + j0m] = 0ull;
    }
  }
  __syncthreads();
  if (tid < C_) {
    int j = tid;
    U[j][j] = 1.f;
    for (int i = j + 1; i < C_; i++) {
      float s = 0.f;
      for (int l = j; l < i; l++) s += U[i][l] * U[j][l];
      U[j][i] = -s;
    }
  }
  __syncthreads();
  for (int idx = tid; idx < C_*32; idx += 256) {
    int i = idx >> 5, e4 = (idx & 31) * 4;
    float s = beta_s[i] * edec[i];
    float4 v = *(const float4*)&Pool[i*132 + e4];
    v.x*=s; v.y*=s; v.z*=s; v.w*=s;
    *(float4*)&Pool[i*132 + e4] = v;
  }
  __syncthreads();
  const int i0 = (tid >> 4) * 4, e0 = (tid & 15) * 8;
  {
    float acc[4][8];
    #pragma unroll
    for (int r = 0; r < 4; r++)
      #pragma unroll
      for (int c = 0; c < 8; c++) acc[r][c] = 0.f;
    for (int j = 0; j < i0; j++) {
      float a0=U[j][i0], a1=U[j][i0+1], a2=U[j][i0+2], a3=U[j][i0+3];
      float4 w0 = *(const float4*)&Pool[j*132 + e0];
      float4 w1 = *(const float4*)&Pool[j*132 + e0 + 4];
      float ww[8] = {w0.x,w0.y,w0.z,w0.w,w1.x,w1.y,w1.z,w1.w};
      float aa[4] = {a0,a1,a2,a3};
      #pragma unroll
      for (int r = 0; r < 4; r++)
        #pragma unroll
        for (int c = 0; c < 8; c++) acc[r][c] += aa[r]*ww[c];
    }
    #pragma unroll
    for (int jj = 0; jj < 4; jj++) {
      int j = i0 + jj;
      float4 w0 = *(const float4*)&Pool[j*132 + e0];
      float4 w1 = *(const float4*)&Pool[j*132 + e0 + 4];
      float ww[8] = {w0.x,w0.y,w0.z,w0.w,w1.x,w1.y,w1.z,w1.w};
      for (int r = jj; r < 4; r++) {
        float a = U[j][i0+r];
        #pragma unroll
        for (int c = 0; c < 8; c++) acc[r][c] += a*ww[c];
      }
    }
    #pragma unroll
    for (int r = 0; r < 4; r++) {
      size_t base = ((size_t)bh*T_ + t0 + i0 + r)*HD_ + e0;
      *(ull_t*)&wkcd_buf[base]   = pack4bf(acc[r][0],acc[r][1],acc[r][2],acc[r][3]);
      *(ull_t*)&wkcd_buf[base+4] = pack4bf(acc[r][4],acc[r][5],acc[r][6],acc[r][7]);
    }
  }
  __syncthreads();
  for (int idx = tid; idx < C_*32; idx += 256) {
    int i = idx >> 5, e4 = (idx & 31) * 4;
    float4 v = *(const float4*)&v_io[((size_t)b*T_ + t0 + i)*D_ + h*HD_ + e4];
    float s = beta_s[i];
    v.x*=s; v.y*=s; v.z*=s; v.w*=s;
    *(float4*)&Pool[i*128 + e4] = v;
  }
  __syncthreads();
  {
    float acc[4][8];
    #pragma unroll
    for (int r = 0; r < 4; r++)
      #pragma unroll
      for (int c = 0; c < 8; c++) acc[r][c] = 0.f;
    for (int j = 0; j < i0; j++) {
      float aa[4] = {U[j][i0], U[j][i0+1], U[j][i0+2], U[j][i0+3]};
      float4 v0 = *(const float4*)&Pool[j*128 + e0];
      float4 v1 = *(const float4*)&Pool[j*128 + e0 + 4];
      float vv[8] = {v0.x,v0.y,v0.z,v0.w,v1.x,v1.y,v1.z,v1.w};
      #pragma unroll
      for (int r = 0; r < 4; r++)
        #pragma unroll
        for (int c = 0; c < 8; c++) acc[r][c] += aa[r]*vv[c];
    }
    #pragma unroll
    for (int jj = 0; jj < 4; jj++) {
      int j = i0 + jj;
      float4 v0 = *(const float4*)&Pool[j*128 + e0];
      float4 v1 = *(const float4*)&Pool[j*128 + e0 + 4];
      float vv[8] = {v0.x,v0.y,v0.z,v0.w,v1.x,v1.y,v1.z,v1.w};
      for (int r = jj; r < 4; r++) {
        float a = U[j][i0+r];
        #pragma unroll
        for (int c = 0; c < 8; c++) acc[r][c] += a*vv[c];
      }
    }
    #pragma unroll
    for (int r = 0; r < 4; r++) {
      size_t base = ((size_t)b*T_ + t0 + i0 + r)*D_ + h*HD_ + e0;
      float4 v0 = {acc[r][0],acc[r][1],acc[r][2],acc[r][3]};
      float4 v1 = {acc[r][4],acc[r][5],acc[r][6],acc[r][7]};
      *(float4*)&v_io[base]     = v0;
      *(float4*)&v_io[base + 4] = v1;
    }
  }
}

// ---------------------------------------------------------------------------
// Kernel 4 (MFMA v2): inter-chunk scan.  grid = BH*8 (16-col e-slices) = 256
// blocks (1/CU), 512 thr (8 waves).  Wave w owns S rows d=w*16..+15 (one
// 16x16 f32x4 acc).  Role split: w0-3 v_new, w4-7 rk@S then o-finish; all
// waves S-update.  K^T for the S-update is loaded DIRECTLY from global x
// (16 scalars/thread, issued phase A, used phase D) -- no LDS transpose, no
// 16-way bank conflicts.  XCD-affinity block decode: the 8 e-slices + 4 bh
// of one XCD share keys/wkcd/attn in its L2.  LDS ~55 KB.
// ---------------------------------------------------------------------------
__global__ __launch_bounds__(512, 2) void k4_mfma(
    const float* __restrict__ x, float* __restrict__ v_io,
    const ushort_t* __restrict__ wkcd_buf, const ushort_t* __restrict__ attn_buf,
    const float* __restrict__ dec_buf, const float* __restrict__ gate_buf,
    const float* __restrict__ innorm_buf) {
  const int bid = blockIdx.x;
  const int xcd = bid & 7, jj = bid >> 3;          // jj 0..31
  const int bh = xcd*4 + (jj >> 3);                // 4 bh per XCD
  const int eq = jj & 7;                           // 8 e-slices
  const int e0b = eq * 16;
  const int b = bh >> 3, h = bh & 7;
  const int tid = threadIdx.x;
  const int w = tid >> 6, lane = tid & 63;
  const int l15 = lane & 15, l4 = lane >> 4;
  const bool lowg = (w < 4);
  const int mw = w & 3;                            // tile index within role group

  __shared__ ushort_t Krm[64*136];   // keys rows t0..t0+63 (rk), [t][d]
  __shared__ ushort_t Wn [64*136];   // -wkcd, [t][d]
  __shared__ ushort_t At [64*72];    // attn, [t][i]
  __shared__ ushort_t Sth[16*136];   // S hi bf16, [e][d]
  __shared__ ushort_t Stl[16*136];   // S lo bf16
  __shared__ ushort_t Vt [16*72];    // v_new^T bf16, [e][t]
  __shared__ float dec_s[64], gate_s[64], sc_s[64], dwn_s[64];

  f32x4 Sacc;                        // S[d=w*16+l4*4+r][e=l15]
  Sacc[0]=0.f; Sacc[1]=0.f; Sacc[2]=0.f; Sacc[3]=0.f;

  float4 kf[4], wf[2], af;
  auto PF = [&](int nn) {            // next-chunk bulk loads -> regs
    const int t0n = nn * C_;
    #pragma unroll
    for (int k = 0; k < 4; k++) {
      int slot = tid + 512*k;
      int row = slot >> 5, q = slot & 31;
      kf[k] = *(const float4*)&x[((size_t)b*T_ + t0n + row)*D_ + h*HD_ + q*4];
    }
    #pragma unroll
    for (int k = 0; k < 2; k++) {
      int p = tid + 512*k;
      int row = p >> 4, cg = p & 15;
      wf[k] = *(const float4*)&wkcd_buf[((size_t)bh*T_ + t0n + row)*HD_ + cg*8];
    }
    af = *(const float4*)&attn_buf[(((size_t)bh*N_ + nn)*C_ + (tid>>3))*C_ + (tid&7)*8];
  };

  PF(0);

  for (int n = 0; n < N_; n++) {
    const int t0 = n * C_;
    // ===== A: stage LDS from PF regs; issue current-chunk loads =====
    #pragma unroll
    for (int k = 0; k < 4; k++) {
      int slot = tid + 512*k;
      int row = slot >> 5, q = slot & 31;
      float4 v = kf[k];
      *(ull_t*)&Krm[row*136 + q*4] = pack4bf(v.x, v.y, v.z, v.w);
    }
    #pragma unroll
    for (int k = 0; k < 2; k++) {
      int p = tid + 512*k;
      int row = p >> 4, cg = p & 15;
      int4 u = *(int4*)&wf[k];
      u.x ^= 0x80008000; u.y ^= 0x80008000; u.z ^= 0x80008000; u.w ^= 0x80008000;
      *(int4*)&Wn[row*136 + cg*8] = u;
    }
    *(int4*)&At[(tid>>3)*72 + (tid&7)*8] = *(int4*)&af;
    // St hi/lo from Sacc
    {
      ull_t ph = 0, pl = 0;
      #pragma unroll
      for (int r = 0; r < 4; r++) {
        float s = Sacc[r];
        ushort_t hb = f2bf(s);
        ushort_t lb = f2bf(s - bfu(hb));
        ph |= (ull_t)hb << (16*r);
        pl |= (ull_t)lb << (16*r);
      }
      *(ull_t*)&Sth[l15*136 + w*16 + l4*4] = ph;
      *(ull_t*)&Stl[l15*136 + w*16 + l4*4] = pl;
    }
    // current-chunk: v' (lower waves), K^T scalars (all waves), smalls
    float vpf[4] = {0.f, 0.f, 0.f, 0.f};
    if (lowg) {
      #pragma unroll
      for (int r = 0; r < 4; r++)
        vpf[r] = v_io[((size_t)b*T_ + t0 + mw*16 + l4*4 + r)*D_ + h*HD_ + e0b + l15];
    }
    float ktf[16];
    #pragma unroll
    for (int ks = 0; ks < 2; ks++)
      #pragma unroll
      for (int j2 = 0; j2 < 8; j2++) {
        int tg = t0 - 1 + ks*32 + l4*8 + j2;
        ktf[ks*8+j2] = (tg >= 0)
            ? x[((size_t)b*T_ + tg)*D_ + h*HD_ + w*16 + l15] : 0.f;
      }
    float ipr = 0.f, icr = 0.f;
    if (tid < 64) {
      size_t g = (size_t)bh*T_ + t0 + tid;
      dec_s[tid]  = dec_buf[g];
      gate_s[tid] = gate_buf[g];
      icr = innorm_buf[g];
      ipr = (t0 - 1 + tid >= 0) ? innorm_buf[g - 1] : 0.f;
    }
    __syncthreads();   // (1)
    if (tid < 64) {
      float dv = dec_s[tid], d63 = dec_s[63];
      sc_s[tid]  = expf(dv) * icr;            // edec[t] * innorm[t0+t]
      dwn_s[tid] = expf(d63 - dv) * ipr;      // exp(declast-dec[t]) * innorm[t0-1+t]
    }
    if (n + 1 < N_) PF(n + 1);                // overlap next-chunk loads
    f32x4 oacc;
    if (lowg) {
      // ===== B (w0-3): v_new rows mw*16.. = v' + (-wkcd)@(Shi+Slo) =====
      f32x4 acc;
      acc[0]=vpf[0]; acc[1]=vpf[1]; acc[2]=vpf[2]; acc[3]=vpf[3];
      #pragma unroll
      for (int ks = 0; ks < 4; ks++) {
        s8v a  = *(const s8v*)&Wn [(mw*16 + l15)*136 + ks*32 + l4*8];
        s8v sh = *(const s8v*)&Sth[l15*136 + ks*32 + l4*8];
        s8v sl = *(const s8v*)&Stl[l15*136 + ks*32 + l4*8];
        acc = __builtin_amdgcn_mfma_f32_16x16x32_bf16(a, sh, acc, 0, 0, 0);
        acc = __builtin_amdgcn_mfma_f32_16x16x32_bf16(a, sl, acc, 0, 0, 0);
      }
      ull_t pv = 0;
      #pragma unroll
      for (int r = 0; r < 4; r++) pv |= (ull_t)f2bf(acc[r]) << (16*r);
      *(ull_t*)&Vt[l15*72 + mw*16 + l4*4] = pv;
    } else {
      // ===== C1 (w4-7): oS = rk@S rows mw*16.. =====
      oacc[0]=0.f; oacc[1]=0.f; oacc[2]=0.f; oacc[3]=0.f;
      #pragma unroll
      for (int ks = 0; ks < 4; ks++) {
        s8v a  = *(const s8v*)&Krm[(mw*16 + l15)*136 + ks*32 + l4*8];
        s8v sh = *(const s8v*)&Sth[l15*136 + ks*32 + l4*8];
        s8v sl = *(const s8v*)&Stl[l15*136 + ks*32 + l4*8];
        oacc = __builtin_amdgcn_mfma_f32_16x16x32_bf16(a, sh, oacc, 0, 0, 0);
        oacc = __builtin_amdgcn_mfma_f32_16x16x32_bf16(a, sl, oacc, 0, 0, 0);
      }
    }
    __syncthreads();   // (2) Vt ready
    if (!lowg) {
      // ===== C2 (w4-7): o = sc*oS + attn@v_new; gate; store =====
      #pragma unroll
      for (int r = 0; r < 4; r++) oacc[r] *= sc_s[mw*16 + l4*4 + r];
      #pragma unroll
      for (int ks = 0; ks < 2; ks++) {
        s8v a  = *(const s8v*)&At[(mw*16 + l15)*72 + ks*32 + l4*8];
        s8v bv = *(const s8v*)&Vt[l15*72 + ks*32 + l4*8];
        oacc = __builtin_amdgcn_mfma_f32_16x16x32_bf16(a, bv, oacc, 0, 0, 0);
      }
      #pragma unroll
      for (int r = 0; r < 4; r++) {
        float g = gate_s[mw*16 + l4*4 + r];
        v_io[((size_t)b*T_ + t0 + mw*16 + l4*4 + r)*D_ + h*HD_ + e0b + l15] = oacc[r] * g;
      }
    }
    // ===== D (all waves): Sacc = el*Sacc + (K^T*dwn)@v_new =====
    {
      float el = expf(dec_s[63]);
      #pragma unroll
      for (int r = 0; r < 4; r++) Sacc[r] *= el;
      #pragma unroll
      for (int ks = 0; ks < 2; ks++) {
        s8v am;
        #pragma unroll
        for (int j2 = 0; j2 < 8; j2++)
          am[j2] = (short)f2bf(ktf[ks*8+j2] * dwn_s[ks*32 + l4*8 + j2]);
        s8v bv = *(const s8v*)&Vt[l15*72 + ks*32 + l4*8];
        Sacc = __builtin_amdgcn_mfma_f32_16x16x32_bf16(am, bv, Sacc, 0, 0, 0);
      }
    }
    __syncthreads();   // (3) protect LDS vs next chunk's staging
  }
}

// ---------------------------------------------------------------------------
extern "C" void kernel_launch(void* const* d_in, const int* in_sizes, int n_in,
                              void* d_out, int out_size, void* d_ws, size_t ws_size,
                              hipStream_t stream) {
  const float* x       = (const float*)d_in[0];
  const float* W_write = (const float*)d_in[1];
  const float* W_gate  = (const float*)d_in[2];
  const float* W_out   = (const float*)d_in[3];
  const float* W_beta  = (const float*)d_in[4];
  const float* W_alpha = (const float*)d_in[5];
  const float* dt_bias = (const float*)d_in[6];
  const float* A_log   = (const float*)d_in[7];
  float* out = (float*)d_out;

  const size_t SZ_BIG   = (size_t)BT_ * D_;
  const size_t SZ_ATTN  = (size_t)BH_ * N_ * C_ * C_;
  const size_t SZ_SMALL = (size_t)BH_ * T_;

  float*    vraw = (float*)d_ws;
  ushort_t* wkcd = (ushort_t*)(vraw + SZ_BIG);
  ushort_t* attn = wkcd + SZ_BIG;
  float*    decb = (float*)(attn + SZ_ATTN);
  float*    gateb  = decb + SZ_SMALL;
  float*    betab  = gateb + SZ_SMALL;
  float*    decayb = betab + SZ_SMALL;
  float*    innorm = decayb + SZ_SMALL;

  const int GEMM_GRID = (BT_/128) * (D_/128);   // 2048, %8==0

  k1_proj<<<BT_, 256, 0, stream>>>(x, W_gate, W_beta, W_alpha, dt_bias, A_log,
                                   gateb, betab, decayb, innorm);
  k_gemm_bf16<<<GEMM_GRID, 256, 0, stream>>>(x, W_write, nullptr, vraw,
                                             BT_, D_, D_);
  k3_chunk<<<BH_*N_, 256, 0, stream>>>(x, vraw, betab, decayb, innorm,
                                       wkcd, attn, decb);
  k4_mfma<<<BH_*8, 512, 0, stream>>>(x, vraw, wkcd, attn, decb, gateb, innorm);
  k_gemm_bf16<<<GEMM_GRID, 256, 0, stream>>>(vraw, W_out, x, out,
                                             BT_, D_, D_);
}

// Round 6
// 1476.251 us; speedup vs baseline: 2.9169x; 1.0073x over previous
//
#include <hip/hip_runtime.h>
#include <math.h>

#define B_ 4
#define T_ 8192
#define D_ 1024
#define H_ 8
#define HD_ 128
#define C_ 64
#define N_ 128
#define BT_ (B_*T_)
#define BH_ (B_*H_)

typedef unsigned short ushort_t;
typedef unsigned long long ull_t;
typedef short s8v __attribute__((ext_vector_type(8)));   // 8 bf16 (4 VGPRs) MFMA A/B frag
typedef float f32x4 __attribute__((ext_vector_type(4))); // MFMA C/D frag

__device__ __forceinline__ float bfu(unsigned int u16) {   // low 16 bits = bf16
  return __uint_as_float(u16 << 16);
}
__device__ __forceinline__ ushort_t f2bf(float f) {
  unsigned int x = __float_as_uint(f);
  x += 0x7FFFu + ((x >> 16) & 1u);
  return (ushort_t)(x >> 16);
}
__device__ __forceinline__ ull_t pack4bf(float a, float b, float c, float d) {
  return (ull_t)f2bf(a) | ((ull_t)f2bf(b) << 16) | ((ull_t)f2bf(c) << 32) | ((ull_t)f2bf(d) << 48);
}

// ---------------------------------------------------------------------------
// Kernel 1: per-token projections -> gate, beta, decay(raw), innorm.
// grid = B*T blocks, 256 threads.
// ---------------------------------------------------------------------------
__global__ __launch_bounds__(256) void k1_proj(
    const float* __restrict__ x, const float* __restrict__ Wg,
    const float* __restrict__ Wb, const float* __restrict__ Wa,
    const float* __restrict__ dt_bias, const float* __restrict__ A_log,
    float* __restrict__ gate_buf, float* __restrict__ beta_buf,
    float* __restrict__ decay_buf, float* __restrict__ innorm_buf) {
  const int row = blockIdx.x;
  const int b = row / T_, t = row % T_;
  const int tid = threadIdx.x;
  __shared__ float xs[D_];
  __shared__ float red[3][H_][4];
  __shared__ float scal[3][H_];
  __shared__ float rnorm[H_];

  ((float4*)xs)[tid] = ((const float4*)(x + (size_t)row * D_))[tid];
  __syncthreads();

  float pg[H_], pb[H_], pa[H_];
  #pragma unroll
  for (int h = 0; h < H_; h++) { pg[h] = 0.f; pb[h] = 0.f; pa[h] = 0.f; }
  for (int i = tid; i < D_; i += 256) {
    float xv = xs[i];
    #pragma unroll
    for (int h = 0; h < H_; h++) {
      pg[h] += xv * Wg[h*D_ + i];
      pb[h] += xv * Wb[h*D_ + i];
      pa[h] += xv * Wa[h*D_ + i];
    }
  }
  const int lane = tid & 63, wv = tid >> 6;
  #pragma unroll
  for (int h = 0; h < H_; h++) {
    float g = pg[h], bb = pb[h], aa = pa[h];
    #pragma unroll
    for (int off = 32; off > 0; off >>= 1) {
      g  += __shfl_down(g, off);
      bb += __shfl_down(bb, off);
      aa += __shfl_down(aa, off);
    }
    if (lane == 0) { red[0][h][wv] = g; red[1][h][wv] = bb; red[2][h][wv] = aa; }
  }
  float pn;
  {
    int hh = tid >> 5, e0 = (tid & 31) * 4;
    const float* xh = xs + hh*HD_ + e0;
    pn = xh[0]*xh[0] + xh[1]*xh[1] + xh[2]*xh[2] + xh[3]*xh[3];
  }
  #pragma unroll
  for (int off = 16; off > 0; off >>= 1) pn += __shfl_down(pn, off, 32);
  __syncthreads();
  if ((tid & 31) == 0) rnorm[tid >> 5] = fmaxf(sqrtf(pn), 1e-12f);
  if (tid < 24) {
    int p = tid >> 3, h = tid & 7;
    scal[p][h] = red[p][h][0] + red[p][h][1] + red[p][h][2] + red[p][h][3];
  }
  __syncthreads();
  if (tid < H_) {
    int h = tid;
    float g  = 1.f / (1.f + expf(-scal[0][h]));
    float be = 1.f / (1.f + expf(-scal[1][h]));
    float z  = scal[2][h] + dt_bias[h];
    float sp = (z > 20.f) ? z : log1pf(expf(z));
    float dc = -expf(A_log[h]) * sp;
    size_t idx = (size_t)(b*H_ + h)*T_ + t;
    gate_buf[idx] = g; beta_buf[idx] = be; decay_buf[idx] = dc;
    innorm_buf[idx] = 1.f / rnorm[h];
  }
}

// ---------------------------------------------------------------------------
// GEMM (bf16 MFMA): C[M,N] = A[M,K] @ W[N,K]^T (+ R).
// 128x128 tile, BK=32, 256 thr (4 waves x 64x64 out).  fp32 inputs converted
// to bf16 during reg->LDS staging.  XCD-aware block swizzle.  LDS 20 KB.
// ---------------------------------------------------------------------------
__global__ __launch_bounds__(256) void k_gemm_bf16(
    const float* __restrict__ A, const float* __restrict__ W,
    const float* __restrict__ R, float* __restrict__ C,
    int M, int N, int K) {
  __shared__ ushort_t La[128*40];   // stride 40 bf16 = 80 B (2-way conflicts only)
  __shared__ ushort_t Lw[128*40];
  const int tid = threadIdx.x;
  const int w = tid >> 6, lane = tid & 63;
  const int l15 = lane & 15, l4 = lane >> 4;
  const int wr = w >> 1, wc = w & 1;          // wave tile: rows wr*64, cols wc*64

  // XCD-aware swizzle (grid is 1-D, nwg % 8 == 0)
  const int nwg = gridDim.x;
  const int NB = N >> 7;
  const int bid = blockIdx.x;
  const int swz = (bid & 7) * (nwg >> 3) + (bid >> 3);
  const int row0 = (swz / NB) * 128, col0 = (swz % NB) * 128;

  f32x4 acc[4][4];
  #pragma unroll
  for (int m = 0; m < 4; m++)
    #pragma unroll
    for (int n = 0; n < 4; n++)
      #pragma unroll
      for (int r = 0; r < 4; r++) acc[m][n][r] = 0.f;

  float4 pa[2][2], pw[2][2];
  auto LOAD = [&](int k0) {
    #pragma unroll
    for (int s = 0; s < 2; s++) {
      int slot = tid + s*256;
      int rw = slot >> 2, kg = (slot & 3) * 8;
      const float* ap = A + (size_t)(row0 + rw)*K + k0 + kg;
      pa[s][0] = *(const float4*)ap; pa[s][1] = *(const float4*)(ap + 4);
      const float* wp = W + (size_t)(col0 + rw)*K + k0 + kg;
      pw[s][0] = *(const float4*)wp; pw[s][1] = *(const float4*)(wp + 4);
    }
  };

  LOAD(0);
  for (int k0 = 0; k0 < K; k0 += 32) {
    // stage regs -> LDS (fp32 -> bf16)
    #pragma unroll
    for (int s = 0; s < 2; s++) {
      int slot = tid + s*256;
      int rw = slot >> 2, kg = (slot & 3) * 8;
      int4 ua, uw;
      ua.x = (int)f2bf(pa[s][0].x) | ((int)f2bf(pa[s][0].y) << 16);
      ua.y = (int)f2bf(pa[s][0].z) | ((int)f2bf(pa[s][0].w) << 16);
      ua.z = (int)f2bf(pa[s][1].x) | ((int)f2bf(pa[s][1].y) << 16);
      ua.w = (int)f2bf(pa[s][1].z) | ((int)f2bf(pa[s][1].w) << 16);
      uw.x = (int)f2bf(pw[s][0].x) | ((int)f2bf(pw[s][0].y) << 16);
      uw.y = (int)f2bf(pw[s][0].z) | ((int)f2bf(pw[s][0].w) << 16);
      uw.z = (int)f2bf(pw[s][1].x) | ((int)f2bf(pw[s][1].y) << 16);
      uw.w = (int)f2bf(pw[s][1].z) | ((int)f2bf(pw[s][1].w) << 16);
      *(int4*)&La[rw*40 + kg] = ua;
      *(int4*)&Lw[rw*40 + kg] = uw;
    }
    __syncthreads();
    if (k0 + 32 < K) LOAD(k0 + 32);    // overlap next-tile loads with MFMA
    s8v af[4], bf[4];
    #pragma unroll
    for (int m = 0; m < 4; m++)
      af[m] = *(const s8v*)&La[(wr*64 + m*16 + l15)*40 + l4*8];
    #pragma unroll
    for (int n = 0; n < 4; n++)
      bf[n] = *(const s8v*)&Lw[(wc*64 + n*16 + l15)*40 + l4*8];
    #pragma unroll
    for (int m = 0; m < 4; m++)
      #pragma unroll
      for (int n = 0; n < 4; n++)
        acc[m][n] = __builtin_amdgcn_mfma_f32_16x16x32_bf16(af[m], bf[n], acc[m][n], 0, 0, 0);
    __syncthreads();
  }

  // epilogue: C row = row0+wr*64+m*16+l4*4+r, col = col0+wc*64+n*16+l15
  #pragma unroll
  for (int m = 0; m < 4; m++) {
    #pragma unroll
    for (int r = 0; r < 4; r++) {
      int row = row0 + wr*64 + m*16 + l4*4 + r;
      size_t base = (size_t)row * N + col0 + wc*64 + l15;
      #pragma unroll
      for (int n = 0; n < 4; n++) {
        float v = acc[m][n][r];
        if (R) v += R[base + n*16];
        C[base + n*16] = v;
      }
    }
  }
}

// ---------------------------------------------------------------------------
// Kernel 3 (MFMA): per-chunk UT transform.  grid = BH*N, 256 thr (4 waves).
// Gram G[i][j]=Ke[i+1]·Ke[j] via MFMA feeds BOTH M (strict lower, scaled by
// beta*e^dec) and attn.  Triangular inverse stays scalar (wave 0).
// wkcd = A@Ws and v' = A@Vb via MFMA with TRANSPOSED B staging ([e][j], row
// stride 72 ushort = 144B, 16B-aligned).  Vb split hi/lo bf16 (protects the
// recurrence input v').  LDS regions aliased: Ke->WsT, Gs->VbT_h, U->VbT_l.
// LDS ~66 KB -> 2 blocks/CU.
// ---------------------------------------------------------------------------
__global__ __launch_bounds__(256) void k3_chunk(
    const float* __restrict__ x, float* __restrict__ v_io,
    const float* __restrict__ beta_buf, const float* __restrict__ decay_buf,
    const float* __restrict__ innorm_buf,
    ushort_t* __restrict__ wkcd_buf, ushort_t* __restrict__ attn_buf,
    float* __restrict__ dec_buf) {
  const int blk = blockIdx.x;
  const int bh = blk >> 7, n = blk & 127;
  const int b = bh >> 3, h = bh & 7;
  const int t0 = n * C_;
  const int tid = threadIdx.x;
  const int w = tid >> 6, lane = tid & 63;
  const int l15 = lane & 15, l4 = lane >> 4;

  __shared__ __align__(16) ushort_t R1[128*72];   // Ke[65][136] bf16; later WsT[128][72]
  __shared__ __align__(16) float    Gs[64*72];    // Gram f32; later VbT_h[128][72] bf16
  __shared__ __align__(16) float    U[C_][74];    // M lower / A^T upper; later VbT_l
  __shared__ __align__(16) ushort_t At[64*72];    // A row-major bf16
  __shared__ float dec_s[C_], beta_s[C_], inn[65], sbw[C_];
  ushort_t* Ke   = R1;                 // stride 136
  ushort_t* WsT  = R1;                 // stride 72
  ushort_t* VbTh = (ushort_t*)Gs;      // stride 72
  ushort_t* VbTl = (ushort_t*)&U[0][0];// stride 72

  // ---- A: global loads ----
  float4 kf[9];
  #pragma unroll
  for (int k = 0; k < 9; k++) {
    int slot = tid + 256*k;
    float4 v = {0.f,0.f,0.f,0.f};
    if (slot < 2080) {
      int row = slot >> 5, q = slot & 31;
      int tg = t0 - 1 + row;
      if (tg >= 0) v = *(const float4*)&x[((size_t)b*T_ + tg)*D_ + h*HD_ + q*4];
    }
    kf[k] = v;
  }
  if (tid < 65) {
    int tg = t0 - 1 + tid;
    inn[tid] = (tg >= 0) ? innorm_buf[(size_t)bh*T_ + tg] : 0.f;
  }
  if (tid >= 192) {
    int i = tid - 192;
    size_t g = (size_t)bh*T_ + t0 + i;
    beta_s[i] = beta_buf[g];
    dec_s[i] = decay_buf[g];
  }
  __syncthreads();   // (1)

  // ---- B: dec inclusive scan (wave 0, shfl) + Ke fill (all) ----
  if (tid < C_) {
    float v = dec_s[tid];
    #pragma unroll
    for (int off = 1; off < 64; off <<= 1) {
      float p = __shfl_up(v, off);
      if (tid >= off) v += p;
    }
    dec_s[tid] = v;
    sbw[tid] = inn[tid] * beta_s[tid] * expf(v);   // wk-row scale: inn*beta*e^dec
    dec_buf[(size_t)bh*T_ + t0 + tid] = v;
  }
  #pragma unroll
  for (int k = 0; k < 9; k++) {
    int slot = tid + 256*k;
    if (slot < 2080) {
      int row = slot >> 5, q = slot & 31;
      float s = inn[row];
      float4 v = kf[k];
      *(ull_t*)&Ke[row*136 + q*4] = pack4bf(v.x*s, v.y*s, v.z*s, v.w*s);
    }
  }
  __syncthreads();   // (2)

  // ---- C: Gram G[i][j] = Ke[i+1]·Ke[j] (64x64, K=128); wave w = row-tile ----
  #pragma unroll
  for (int tj = 0; tj < 4; tj++) {
    f32x4 acc; acc[0]=0.f; acc[1]=0.f; acc[2]=0.f; acc[3]=0.f;
    #pragma unroll
    for (int ks = 0; ks < 4; ks++) {
      s8v a  = *(const s8v*)&Ke[(w*16 + l15 + 1)*136 + ks*32 + l4*8];
      s8v bv = *(const s8v*)&Ke[(tj*16 + l15)*136 + ks*32 + l4*8];
      acc = __builtin_amdgcn_mfma_f32_16x16x32_bf16(a, bv, acc, 0, 0, 0);
    }
    #pragma unroll
    for (int r = 0; r < 4; r++)
      Gs[(w*16 + l4*4 + r)*72 + tj*16 + l15] = acc[r];
  }
  __syncthreads();   // (3)

  // ---- D: U strict-lower (M) + attn global out ----
  #pragma unroll
  for (int k = 0; k < 16; k++) {
    int idx = tid + 256*k;
    int i = idx >> 6, j = idx & 63;
    float ed = expf(dec_s[i] - dec_s[j]);
    float g2 = Gs[i*72 + j];                         // Ke[i+1]·Ke[j] = rk[i]·wk[j]
    attn_buf[(((size_t)bh*N_ + n)*C_ + i)*C_ + j] = (j <= i) ? f2bf(g2*ed) : (ushort_t)0;
    if (j < i) U[i][j] = Gs[(i-1)*72 + j] * beta_s[i] * ed;   // wk[i]·wk[j] row
  }
  __syncthreads();   // (4)

  // ---- E: forward substitution (wave 0): column j of A in U[j][i] upper ----
  if (tid < C_) {
    int j = tid;
    U[j][j] = 1.f;
    for (int i = j + 1; i < C_; i++) {
      float s = 0.f;
      for (int l = j; l < i; l++) s += U[i][l] * U[j][l];
      U[j][i] = -s;
    }
  }
  __syncthreads();   // (5)

  // ---- F1: At[i][j] = A[i][j] = U[j][i] (j<=i), bf16 ----
  #pragma unroll
  for (int k = 0; k < 16; k++) {
    int idx = tid + 256*k;
    int i = idx >> 6, j = idx & 63;
    At[i*72 + j] = (j <= i) ? f2bf(U[j][i]) : (ushort_t)0;
  }
  __syncthreads();   // (5b) U dead -> VbT_l may overwrite

  // ---- F2: transposed staging: WsT (x, L2-hot), VbT hi/lo (v_io) ----
  #pragma unroll
  for (int k = 0; k < 8; k++) {
    int slot = tid + 256*k;          // 2048 = 128 e x 16 row-groups
    int rg = slot >> 7, e = slot & 127;
    float wv[4];
    #pragma unroll
    for (int c = 0; c < 4; c++) {
      int j = rg*4 + c;
      int tg = t0 - 1 + j;
      wv[c] = (tg >= 0) ? x[((size_t)b*T_ + tg)*D_ + h*HD_ + e] * sbw[j] : 0.f;
    }
    *(ull_t*)&WsT[e*72 + rg*4] = pack4bf(wv[0], wv[1], wv[2], wv[3]);
    ull_t ph = 0, pl = 0;
    #pragma unroll
    for (int c = 0; c < 4; c++) {
      int j = rg*4 + c;
      float vv = v_io[((size_t)b*T_ + t0 + j)*D_ + h*HD_ + e] * beta_s[j];
      ushort_t hb = f2bf(vv);
      ushort_t lb = f2bf(vv - bfu(hb));
      ph |= (ull_t)hb << (16*c);
      pl |= (ull_t)lb << (16*c);
    }
    *(ull_t*)&VbTh[e*72 + rg*4] = ph;
    *(ull_t*)&VbTl[e*72 + rg*4] = pl;
  }
  __syncthreads();   // (6)

  // ---- G: wkcd = A@Ws (bf16 out); v' = A@(Vb_h+Vb_l) (fp32, in place) ----
  #pragma unroll
  for (int tj = 0; tj < 8; tj++) {
    f32x4 acc; acc[0]=0.f; acc[1]=0.f; acc[2]=0.f; acc[3]=0.f;
    #pragma unroll
    for (int ks = 0; ks < 2; ks++) {
      s8v a  = *(const s8v*)&At [(w*16 + l15)*72 + ks*32 + l4*8];
      s8v bv = *(const s8v*)&WsT[(tj*16 + l15)*72 + ks*32 + l4*8];
      acc = __builtin_amdgcn_mfma_f32_16x16x32_bf16(a, bv, acc, 0, 0, 0);
    }
    #pragma unroll
    for (int r = 0; r < 4; r++) {
      int i = w*16 + l4*4 + r, e = tj*16 + l15;
      wkcd_buf[((size_t)bh*T_ + t0 + i)*HD_ + e] = f2bf(acc[r]);
    }
  }
  #pragma unroll
  for (int tj = 0; tj < 8; tj++) {
    f32x4 acc; acc[0]=0.f; acc[1]=0.f; acc[2]=0.f; acc[3]=0.f;
    #pragma unroll
    for (int ks = 0; ks < 2; ks++) {
      s8v a  = *(const s8v*)&At  [(w*16 + l15)*72 + ks*32 + l4*8];
      s8v bh16 = *(const s8v*)&VbTh[(tj*16 + l15)*72 + ks*32 + l4*8];
      s8v bl16 = *(const s8v*)&VbTl[(tj*16 + l15)*72 + ks*32 + l4*8];
      acc = __builtin_amdgcn_mfma_f32_16x16x32_bf16(a, bh16, acc, 0, 0, 0);
      acc = __builtin_amdgcn_mfma_f32_16x16x32_bf16(a, bl16, acc, 0, 0, 0);
    }
    #pragma unroll
    for (int r = 0; r < 4; r++) {
      int i = w*16 + l4*4 + r, e = tj*16 + l15;
      v_io[((size_t)b*T_ + t0 + i)*D_ + h*HD_ + e] = acc[r];
    }
  }
}

// ---------------------------------------------------------------------------
// Kernel 4 (MFMA v2): inter-chunk scan.  grid = BH*8 (16-col e-slices) = 256
// blocks (1/CU), 512 thr (8 waves).  See R5 notes.
// ---------------------------------------------------------------------------
__global__ __launch_bounds__(512, 2) void k4_mfma(
    const float* __restrict__ x, float* __restrict__ v_io,
    const ushort_t* __restrict__ wkcd_buf, const ushort_t* __restrict__ attn_buf,
    const float* __restrict__ dec_buf, const float* __restrict__ gate_buf,
    const float* __restrict__ innorm_buf) {
  const int bid = blockIdx.x;
  const int xcd = bid & 7, jj = bid >> 3;
  const int bh = xcd*4 + (jj >> 3);
  const int eq = jj & 7;
  const int e0b = eq * 16;
  const int b = bh >> 3, h = bh & 7;
  const int tid = threadIdx.x;
  const int w = tid >> 6, lane = tid & 63;
  const int l15 = lane & 15, l4 = lane >> 4;
  const bool lowg = (w < 4);
  const int mw = w & 3;

  __shared__ ushort_t Krm[64*136];
  __shared__ ushort_t Wn [64*136];
  __shared__ ushort_t At [64*72];
  __shared__ ushort_t Sth[16*136];
  __shared__ ushort_t Stl[16*136];
  __shared__ ushort_t Vt [16*72];
  __shared__ float dec_s[64], gate_s[64], sc_s[64], dwn_s[64];

  f32x4 Sacc;
  Sacc[0]=0.f; Sacc[1]=0.f; Sacc[2]=0.f; Sacc[3]=0.f;

  float4 kf[4], wf[2], af;
  auto PF = [&](int nn) {
    const int t0n = nn * C_;
    #pragma unroll
    for (int k = 0; k < 4; k++) {
      int slot = tid + 512*k;
      int row = slot >> 5, q = slot & 31;
      kf[k] = *(const float4*)&x[((size_t)b*T_ + t0n + row)*D_ + h*HD_ + q*4];
    }
    #pragma unroll
    for (int k = 0; k < 2; k++) {
      int p = tid + 512*k;
      int row = p >> 4, cg = p & 15;
      wf[k] = *(const float4*)&wkcd_buf[((size_t)bh*T_ + t0n + row)*HD_ + cg*8];
    }
    af = *(const float4*)&attn_buf[(((size_t)bh*N_ + nn)*C_ + (tid>>3))*C_ + (tid&7)*8];
  };

  PF(0);

  for (int n = 0; n < N_; n++) {
    const int t0 = n * C_;
    #pragma unroll
    for (int k = 0; k < 4; k++) {
      int slot = tid + 512*k;
      int row = slot >> 5, q = slot & 31;
      float4 v = kf[k];
      *(ull_t*)&Krm[row*136 + q*4] = pack4bf(v.x, v.y, v.z, v.w);
    }
    #pragma unroll
    for (int k = 0; k < 2; k++) {
      int p = tid + 512*k;
      int row = p >> 4, cg = p & 15;
      int4 u = *(int4*)&wf[k];
      u.x ^= 0x80008000; u.y ^= 0x80008000; u.z ^= 0x80008000; u.w ^= 0x80008000;
      *(int4*)&Wn[row*136 + cg*8] = u;
    }
    *(int4*)&At[(tid>>3)*72 + (tid&7)*8] = *(int4*)&af;
    {
      ull_t ph = 0, pl = 0;
      #pragma unroll
      for (int r = 0; r < 4; r++) {
        float s = Sacc[r];
        ushort_t hb = f2bf(s);
        ushort_t lb = f2bf(s - bfu(hb));
        ph |= (ull_t)hb << (16*r);
        pl |= (ull_t)lb << (16*r);
      }
      *(ull_t*)&Sth[l15*136 + w*16 + l4*4] = ph;
      *(ull_t*)&Stl[l15*136 + w*16 + l4*4] = pl;
    }
    float vpf[4] = {0.f, 0.f, 0.f, 0.f};
    if (lowg) {
      #pragma unroll
      for (int r = 0; r < 4; r++)
        vpf[r] = v_io[((size_t)b*T_ + t0 + mw*16 + l4*4 + r)*D_ + h*HD_ + e0b + l15];
    }
    float ktf[16];
    #pragma unroll
    for (int ks = 0; ks < 2; ks++)
      #pragma unroll
      for (int j2 = 0; j2 < 8; j2++) {
        int tg = t0 - 1 + ks*32 + l4*8 + j2;
        ktf[ks*8+j2] = (tg >= 0)
            ? x[((size_t)b*T_ + tg)*D_ + h*HD_ + w*16 + l15] : 0.f;
      }
    float ipr = 0.f, icr = 0.f;
    if (tid < 64) {
      size_t g = (size_t)bh*T_ + t0 + tid;
      dec_s[tid]  = dec_buf[g];
      gate_s[tid] = gate_buf[g];
      icr = innorm_buf[g];
      ipr = (t0 - 1 + tid >= 0) ? innorm_buf[g - 1] : 0.f;
    }
    __syncthreads();   // (1)
    if (tid < 64) {
      float dv = dec_s[tid], d63 = dec_s[63];
      sc_s[tid]  = expf(dv) * icr;
      dwn_s[tid] = expf(d63 - dv) * ipr;
    }
    if (n + 1 < N_) PF(n + 1);
    f32x4 oacc;
    if (lowg) {
      f32x4 acc;
      acc[0]=vpf[0]; acc[1]=vpf[1]; acc[2]=vpf[2]; acc[3]=vpf[3];
      #pragma unroll
      for (int ks = 0; ks < 4; ks++) {
        s8v a  = *(const s8v*)&Wn [(mw*16 + l15)*136 + ks*32 + l4*8];
        s8v sh = *(const s8v*)&Sth[l15*136 + ks*32 + l4*8];
        s8v sl = *(const s8v*)&Stl[l15*136 + ks*32 + l4*8];
        acc = __builtin_amdgcn_mfma_f32_16x16x32_bf16(a, sh, acc, 0, 0, 0);
        acc = __builtin_amdgcn_mfma_f32_16x16x32_bf16(a, sl, acc, 0, 0, 0);
      }
      ull_t pv = 0;
      #pragma unroll
      for (int r = 0; r < 4; r++) pv |= (ull_t)f2bf(acc[r]) << (16*r);
      *(ull_t*)&Vt[l15*72 + mw*16 + l4*4] = pv;
    } else {
      oacc[0]=0.f; oacc[1]=0.f; oacc[2]=0.f; oacc[3]=0.f;
      #pragma unroll
      for (int ks = 0; ks < 4; ks++) {
        s8v a  = *(const s8v*)&Krm[(mw*16 + l15)*136 + ks*32 + l4*8];
        s8v sh = *(const s8v*)&Sth[l15*136 + ks*32 + l4*8];
        s8v sl = *(const s8v*)&Stl[l15*136 + ks*32 + l4*8];
        oacc = __builtin_amdgcn_mfma_f32_16x16x32_bf16(a, sh, oacc, 0, 0, 0);
        oacc = __builtin_amdgcn_mfma_f32_16x16x32_bf16(a, sl, oacc, 0, 0, 0);
      }
    }
    __syncthreads();   // (2)
    if (!lowg) {
      #pragma unroll
      for (int r = 0; r < 4; r++) oacc[r] *= sc_s[mw*16 + l4*4 + r];
      #pragma unroll
      for (int ks = 0; ks < 2; ks++) {
        s8v a  = *(const s8v*)&At[(mw*16 + l15)*72 + ks*32 + l4*8];
        s8v bv = *(const s8v*)&Vt[l15*72 + ks*32 + l4*8];
        oacc = __builtin_amdgcn_mfma_f32_16x16x32_bf16(a, bv, oacc, 0, 0, 0);
      }
      #pragma unroll
      for (int r = 0; r < 4; r++) {
        float g = gate_s[mw*16 + l4*4 + r];
        v_io[((size_t)b*T_ + t0 + mw*16 + l4*4 + r)*D_ + h*HD_ + e0b + l15] = oacc[r] * g;
      }
    }
    {
      float el = expf(dec_s[63]);
      #pragma unroll
      for (int r = 0; r < 4; r++) Sacc[r] *= el;
      #pragma unroll
      for (int ks = 0; ks < 2; ks++) {
        s8v am;
        #pragma unroll
        for (int j2 = 0; j2 < 8; j2++)
          am[j2] = (short)f2bf(ktf[ks*8+j2] * dwn_s[ks*32 + l4*8 + j2]);
        s8v bv = *(const s8v*)&Vt[l15*72 + ks*32 + l4*8];
        Sacc = __builtin_amdgcn_mfma_f32_16x16x32_bf16(am, bv, Sacc, 0, 0, 0);
      }
    }
    __syncthreads();   // (3)
  }
}

// ---------------------------------------------------------------------------
extern "C" void kernel_launch(void* const* d_in, const int* in_sizes, int n_in,
                              void* d_out, int out_size, void* d_ws, size_t ws_size,
                              hipStream_t stream) {
  const float* x       = (const float*)d_in[0];
  const float* W_write = (const float*)d_in[1];
  const float* W_gate  = (const float*)d_in[2];
  const float* W_out   = (const float*)d_in[3];
  const float* W_beta  = (const float*)d_in[4];
  const float* W_alpha = (const float*)d_in[5];
  const float* dt_bias = (const float*)d_in[6];
  const float* A_log   = (const float*)d_in[7];
  float* out = (float*)d_out;

  const size_t SZ_BIG   = (size_t)BT_ * D_;
  const size_t SZ_ATTN  = (size_t)BH_ * N_ * C_ * C_;
  const size_t SZ_SMALL = (size_t)BH_ * T_;

  float*    vraw = (float*)d_ws;
  ushort_t* wkcd = (ushort_t*)(vraw + SZ_BIG);
  ushort_t* attn = wkcd + SZ_BIG;
  float*    decb = (float*)(attn + SZ_ATTN);
  float*    gateb  = decb + SZ_SMALL;
  float*    betab  = gateb + SZ_SMALL;
  float*    decayb = betab + SZ_SMALL;
  float*    innorm = decayb + SZ_SMALL;

  const int GEMM_GRID = (BT_/128) * (D_/128);   // 2048, %8==0

  k1_proj<<<BT_, 256, 0, stream>>>(x, W_gate, W_beta, W_alpha, dt_bias, A_log,
                                   gateb, betab, decayb, innorm);
  k_gemm_bf16<<<GEMM_GRID, 256, 0, stream>>>(x, W_write, nullptr, vraw,
                                             BT_, D_, D_);
  k3_chunk<<<BH_*N_, 256, 0, stream>>>(x, vraw, betab, decayb, innorm,
                                       wkcd, attn, decb);
  k4_mfma<<<BH_*8, 512, 0, stream>>>(x, vraw, wkcd, attn, decb, gateb, innorm);
  k_gemm_bf16<<<GEMM_GRID, 256, 0, stream>>>(vraw, W_out, x, out,
                                             BT_, D_, D_);
}